// Round 1
// baseline (435.116 us; speedup 1.0000x reference)
//
#include <hip/hip_runtime.h>

// ---------------------------------------------------------------------------
// Sizes (compile-time): B=8, N=64, FD=128, HD=256, MD=64, D=320, NM=6, FS=80
// rows = B*N = 512
// ---------------------------------------------------------------------------

// ---- JAX threefry2x32 (20 rounds), key = [0, 42] ---------------------------
__device__ __forceinline__ void threefry2x32(unsigned k0, unsigned k1,
                                             unsigned& x0, unsigned& x1) {
  const unsigned ks0 = k0, ks1 = k1, ks2 = k0 ^ k1 ^ 0x1BD11BDAu;
  x0 += ks0; x1 += ks1;
#define TFR(r) { x0 += x1; x1 = (x1 << (r)) | (x1 >> (32 - (r))); x1 ^= x0; }
  TFR(13) TFR(15) TFR(26) TFR(6)  x0 += ks1; x1 += ks2 + 1u;
  TFR(17) TFR(29) TFR(16) TFR(24) x0 += ks2; x1 += ks0 + 2u;
  TFR(13) TFR(15) TFR(26) TFR(6)  x0 += ks0; x1 += ks1 + 3u;
  TFR(17) TFR(29) TFR(16) TFR(24) x0 += ks1; x1 += ks2 + 4u;
  TFR(13) TFR(15) TFR(26) TFR(6)  x0 += ks2; x1 += ks0 + 5u;
#undef TFR
}

// XLA f32 ErfInv (Giles polynomial) — matches CPU/GPU XLA lowering
__device__ __forceinline__ float erfinv_xla(float x) {
  float w = -logf((1.0f - x) * (1.0f + x));
  float p;
  if (w < 5.0f) {
    w = w - 2.5f;
    p = 2.81022636e-08f;
    p = fmaf(p, w, 3.43273939e-07f);
    p = fmaf(p, w, -3.5233877e-06f);
    p = fmaf(p, w, -4.39150654e-06f);
    p = fmaf(p, w, 0.00021858087f);
    p = fmaf(p, w, -0.00125372503f);
    p = fmaf(p, w, -0.00417768164f);
    p = fmaf(p, w, 0.246640727f);
    p = fmaf(p, w, 1.50140941f);
  } else {
    w = sqrtf(w) - 3.0f;
    p = -0.000200214257f;
    p = fmaf(p, w, 0.000100950558f);
    p = fmaf(p, w, 0.00134934322f);
    p = fmaf(p, w, -0.00367342844f);
    p = fmaf(p, w, 0.00573950773f);
    p = fmaf(p, w, -0.0076224613f);
    p = fmaf(p, w, 0.00943887047f);
    p = fmaf(p, w, 1.00167406f);
    p = fmaf(p, w, 2.83297682f);
  }
  return p * x;
}

// jax.random.normal(key(42), (8,64,64), f32), partitionable threefry:
// bits[i] = tf2x32(k=[0,42], x=[hi32(i)=0, lo32(i)=i]); fold out0^out1.
__device__ __forceinline__ float jax_normal42(unsigned idx) {
  unsigned x0 = 0u, x1 = idx;
  threefry2x32(0u, 42u, x0, x1);
  unsigned bits = x0 ^ x1;
  float f = __uint_as_float((bits >> 9) | 0x3f800000u) - 1.0f;  // [0,1)
  const float lo = -0.99999994f;   // nextafter(-1,0) in f32
  float u = fmaxf(lo, f * 2.0f + lo);  // (hi-lo) rounds to exactly 2.0f
  return 1.41421356237f * erfinv_xla(u);
}

// ---------------------------------------------------------------------------
// K1: object encoder -> ctx[:, 0:256] = emb ; ctx[:, 256:320] = sampled
// grid 128, block 256 (4 rows/block)
// ---------------------------------------------------------------------------
__global__ __launch_bounds__(256)
void k_encoder(const float* __restrict__ feat, const float* __restrict__ attr,
               const float* __restrict__ W1, const float* __restrict__ b1,
               const float* __restrict__ W2, const float* __restrict__ b2,
               float* __restrict__ ctx) {
  __shared__ float s_in[4][136];
  __shared__ float s_h1[4][256];
  const int r0 = blockIdx.x * 4;
  const int t = threadIdx.x;
  for (int r = 0; r < 4; ++r) {
    if (t < 128)      s_in[r][t] = feat[(r0 + r) * 128 + t];
    else if (t < 136) s_in[r][t] = attr[(r0 + r) * 8 + (t - 128)];
  }
  __syncthreads();
  float acc[4];
#pragma unroll
  for (int r = 0; r < 4; ++r) acc[r] = b1[t];
  for (int k = 0; k < 136; ++k) {
    const float w = W1[k * 256 + t];
#pragma unroll
    for (int r = 0; r < 4; ++r) acc[r] = fmaf(s_in[r][k], w, acc[r]);
  }
#pragma unroll
  for (int r = 0; r < 4; ++r) s_h1[r][t] = fmaxf(acc[r], 0.0f);
  __syncthreads();
#pragma unroll
  for (int r = 0; r < 4; ++r) acc[r] = b2[t];
  for (int k = 0; k < 256; ++k) {
    const float w = W2[k * 256 + t];
#pragma unroll
    for (int r = 0; r < 4; ++r) acc[r] = fmaf(s_h1[r][k], w, acc[r]);
  }
#pragma unroll
  for (int r = 0; r < 4; ++r) ctx[(r0 + r) * 320 + t] = fmaxf(acc[r], 0.0f);
  if (t < 64) {
    for (int r = 0; r < 4; ++r)
      ctx[(r0 + r) * 320 + 256 + t] = jax_normal42((unsigned)((r0 + r) * 64 + t));
  }
}

// ---------------------------------------------------------------------------
// K2: P = ctx @ W1[0:320] + b1 ; Q = ctx @ W1[320:640]
// grid 128, block 320 (4 rows/block)
// ---------------------------------------------------------------------------
__global__ __launch_bounds__(320)
void k_pq(const float* __restrict__ ctx, const float* __restrict__ W1,
          const float* __restrict__ b1, float* __restrict__ P,
          float* __restrict__ Q) {
  __shared__ float s_c[4][320];
  const int r0 = blockIdx.x * 4;
  const int t = threadIdx.x;
#pragma unroll
  for (int r = 0; r < 4; ++r) s_c[r][t] = ctx[(r0 + r) * 320 + t];
  __syncthreads();
  float p[4], q[4];
#pragma unroll
  for (int r = 0; r < 4; ++r) { p[r] = b1[t]; q[r] = 0.0f; }
  for (int k = 0; k < 320; ++k) {
    const float wp = W1[k * 320 + t];
    const float wq = W1[(320 + k) * 320 + t];
#pragma unroll
    for (int r = 0; r < 4; ++r) {
      const float c = s_c[r][k];
      p[r] = fmaf(c, wp, p[r]);
      q[r] = fmaf(c, wq, q[r]);
    }
  }
#pragma unroll
  for (int r = 0; r < 4; ++r) {
    P[(r0 + r) * 320 + t] = p[r];
    Q[(r0 + r) * 320 + t] = q[r];
  }
}

// ---------------------------------------------------------------------------
// K3: edge MLP layer2 + masked mean (partial over half the j range)
// grid 1024 = (row=512) x (half=2), block 320
// h1(j,t) = relu(P[i,t] + Q[j,t] + rx*W1[640,t] + ry*W1[641,t])
// aggP[bx,t] = sum_{j in half, j!=i} relu(h1[j,:] @ W2[:,t] + b2[t])
// ---------------------------------------------------------------------------
__global__ __launch_bounds__(320)
void k_edge(const float* __restrict__ P, const float* __restrict__ Q,
            const float* __restrict__ pos, const float* __restrict__ W1,
            const float* __restrict__ W2, const float* __restrict__ b2,
            float* __restrict__ aggP) {
  __shared__ __align__(16) float s_h1[32][320];
  __shared__ float s_w0[320], s_w1[320];
  __shared__ float s_pos[128];
  const int bx = blockIdx.x;
  const int row = bx >> 1, half = bx & 1;
  const int b = row >> 6, i = row & 63;
  const int t = threadIdx.x;
  s_w0[t] = W1[640 * 320 + t];
  s_w1[t] = W1[641 * 320 + t];
  if (t < 128) s_pos[t] = pos[b * 128 + t];
  __syncthreads();
  const float Pi = P[row * 320 + t];
  const float px = s_pos[2 * i], py = s_pos[2 * i + 1];
  const int j0 = half * 32;
  for (int jj = 0; jj < 32; ++jj) {
    const int j = j0 + jj;
    const float rx = px - s_pos[2 * j];
    const float ry = py - s_pos[2 * j + 1];
    float v = Pi + Q[(b * 64 + j) * 320 + t];
    v = fmaf(rx, s_w0[t], v);
    v = fmaf(ry, s_w1[t], v);
    s_h1[jj][t] = fmaxf(v, 0.0f);
  }
  __syncthreads();
  float acc[32];
#pragma unroll
  for (int jj = 0; jj < 32; ++jj) acc[jj] = 0.0f;
  for (int k = 0; k < 320; k += 4) {
    const float w0 = W2[(k + 0) * 320 + t];
    const float w1 = W2[(k + 1) * 320 + t];
    const float w2 = W2[(k + 2) * 320 + t];
    const float w3 = W2[(k + 3) * 320 + t];
#pragma unroll
    for (int jj = 0; jj < 32; ++jj) {
      const float4 hq = *reinterpret_cast<const float4*>(&s_h1[jj][k]);
      acc[jj] = fmaf(hq.x, w0, acc[jj]);
      acc[jj] = fmaf(hq.y, w1, acc[jj]);
      acc[jj] = fmaf(hq.z, w2, acc[jj]);
      acc[jj] = fmaf(hq.w, w3, acc[jj]);
    }
  }
  const float bb2 = b2[t];
  float s = 0.0f;
#pragma unroll
  for (int jj = 0; jj < 32; ++jj) {
    if (j0 + jj != i) s += fmaxf(acc[jj] + bb2, 0.0f);
  }
  aggP[bx * 320 + t] = s;  // raw partial sum; /63 applied in GRU kernel
}

// ---------------------------------------------------------------------------
// K4: GRUCell.  grid 128, block 320 (4 rows/block)
// ---------------------------------------------------------------------------
__global__ __launch_bounds__(320)
void k_gru(const float* __restrict__ ctx, const float* __restrict__ aggP,
           const float* __restrict__ Wih, const float* __restrict__ Whh,
           const float* __restrict__ bih, const float* __restrict__ bhh,
           float* __restrict__ h) {
  __shared__ float s_x[4][640];
  const int r0 = blockIdx.x * 4;
  const int t = threadIdx.x;
  float cself[4];
#pragma unroll
  for (int r = 0; r < 4; ++r) {
    const int row = r0 + r;
    const float c = ctx[row * 320 + t];
    cself[r] = c;
    s_x[r][t] = c;
    s_x[r][320 + t] =
        (aggP[(2 * row) * 320 + t] + aggP[(2 * row + 1) * 320 + t]) * (1.0f / 63.0f);
  }
  __syncthreads();
  float gr[4], gz[4], gn[4];
#pragma unroll
  for (int r = 0; r < 4; ++r) { gr[r] = bih[t]; gz[r] = bih[320 + t]; gn[r] = bih[640 + t]; }
  for (int k = 0; k < 640; ++k) {
    const float wr = Wih[k * 960 + t];
    const float wz = Wih[k * 960 + 320 + t];
    const float wn = Wih[k * 960 + 640 + t];
#pragma unroll
    for (int r = 0; r < 4; ++r) {
      const float x = s_x[r][k];
      gr[r] = fmaf(x, wr, gr[r]);
      gz[r] = fmaf(x, wz, gz[r]);
      gn[r] = fmaf(x, wn, gn[r]);
    }
  }
  float hr[4], hz[4], hn[4];
#pragma unroll
  for (int r = 0; r < 4; ++r) { hr[r] = bhh[t]; hz[r] = bhh[320 + t]; hn[r] = bhh[640 + t]; }
  for (int k = 0; k < 320; ++k) {
    const float wr = Whh[k * 960 + t];
    const float wz = Whh[k * 960 + 320 + t];
    const float wn = Whh[k * 960 + 640 + t];
#pragma unroll
    for (int r = 0; r < 4; ++r) {
      const float x = s_x[r][k];
      hr[r] = fmaf(x, wr, hr[r]);
      hz[r] = fmaf(x, wz, hz[r]);
      hn[r] = fmaf(x, wn, hn[r]);
    }
  }
#pragma unroll
  for (int r = 0; r < 4; ++r) {
    const float rr = 1.0f / (1.0f + expf(-(gr[r] + hr[r])));
    const float zz = 1.0f / (1.0f + expf(-(gz[r] + hz[r])));
    const float nn = tanhf(fmaf(rr, hn[r], gn[r]));
    h[(r0 + r) * 320 + t] = (1.0f - zz) * nn + zz * cself[r];
  }
}

// ---------------------------------------------------------------------------
// K5a: mode head + softmax.  grid 512, block 320
// ---------------------------------------------------------------------------
__global__ __launch_bounds__(320)
void k_mode(const float* __restrict__ h, const float* __restrict__ W1,
            const float* __restrict__ b1, const float* __restrict__ W2,
            const float* __restrict__ b2, float* __restrict__ out) {
  __shared__ float s_h[320];
  __shared__ float s_m[320];
  __shared__ float s_l[6];
  const int row = blockIdx.x;
  const int t = threadIdx.x;
  s_h[t] = h[row * 320 + t];
  __syncthreads();
  float a = b1[t];
  for (int k = 0; k < 320; ++k) a = fmaf(s_h[k], W1[k * 320 + t], a);
  s_m[t] = fmaxf(a, 0.0f);
  __syncthreads();
  if (t < 6) {
    float l = b2[t];
    for (int k = 0; k < 320; ++k) l = fmaf(s_m[k], W2[k * 6 + t], l);
    s_l[t] = l;
  }
  __syncthreads();
  if (t < 6) {
    float mx = s_l[0];
#pragma unroll
    for (int q = 1; q < 6; ++q) mx = fmaxf(mx, s_l[q]);
    float sum = 0.0f;
#pragma unroll
    for (int q = 0; q < 6; ++q) sum += expf(s_l[q] - mx);
    out[491520 + row * 6 + t] = expf(s_l[t] - mx) / sum;
  }
}

// ---------------------------------------------------------------------------
// K5b: trajectory head.  grid (128, 6), block 320 (4 rows/block)
// ---------------------------------------------------------------------------
__global__ __launch_bounds__(320)
void k_traj(const float* __restrict__ h, const float* __restrict__ W1,
            const float* __restrict__ b1, const float* __restrict__ W2,
            const float* __restrict__ b2, float* __restrict__ out) {
  __shared__ float s_h[4][320];
  __shared__ float s_t[4][320];
  const int r0 = blockIdx.x * 4;
  const int m = blockIdx.y;
  const int t = threadIdx.x;
#pragma unroll
  for (int r = 0; r < 4; ++r) s_h[r][t] = h[(r0 + r) * 320 + t];
  __syncthreads();
  float acc[4];
#pragma unroll
  for (int r = 0; r < 4; ++r) acc[r] = b1[m * 320 + t];
  const float* w1 = W1 + m * 320 * 320;
  for (int k = 0; k < 320; ++k) {
    const float w = w1[k * 320 + t];
#pragma unroll
    for (int r = 0; r < 4; ++r) acc[r] = fmaf(s_h[r][k], w, acc[r]);
  }
#pragma unroll
  for (int r = 0; r < 4; ++r) s_t[r][t] = fmaxf(acc[r], 0.0f);
  __syncthreads();
  if (t < 160) {
    float o[4];
#pragma unroll
    for (int r = 0; r < 4; ++r) o[r] = b2[m * 160 + t];
    const float* w2 = W2 + m * 320 * 160;
    for (int k = 0; k < 320; ++k) {
      const float w = w2[k * 160 + t];
#pragma unroll
      for (int r = 0; r < 4; ++r) o[r] = fmaf(s_t[r][k], w, o[r]);
    }
#pragma unroll
    for (int r = 0; r < 4; ++r) out[((r0 + r) * 6 + m) * 160 + t] = o[r];
  }
}

// ---------------------------------------------------------------------------
extern "C" void kernel_launch(void* const* d_in, const int* in_sizes, int n_in,
                              void* d_out, int out_size, void* d_ws, size_t ws_size,
                              hipStream_t stream) {
  (void)in_sizes; (void)n_in; (void)out_size; (void)ws_size;
  const float* feat  = (const float*)d_in[0];
  const float* attr  = (const float*)d_in[1];
  // d_in[2] perception_features: dead code in the reference (conv output unused)
  const float* pos   = (const float*)d_in[3];
  const float* encW1 = (const float*)d_in[4];
  const float* encb1 = (const float*)d_in[5];
  const float* encW2 = (const float*)d_in[6];
  const float* encb2 = (const float*)d_in[7];
  // d_in[8..11] conv weights: unused
  const float* edgW1 = (const float*)d_in[12];
  const float* edgb1 = (const float*)d_in[13];
  const float* edgW2 = (const float*)d_in[14];
  const float* edgb2 = (const float*)d_in[15];
  const float* Wih   = (const float*)d_in[16];
  const float* Whh   = (const float*)d_in[17];
  const float* bih   = (const float*)d_in[18];
  const float* bhh   = (const float*)d_in[19];
  const float* mW1   = (const float*)d_in[20];
  const float* mb1   = (const float*)d_in[21];
  const float* mW2   = (const float*)d_in[22];
  const float* mb2   = (const float*)d_in[23];
  const float* tW1   = (const float*)d_in[24];
  const float* tb1   = (const float*)d_in[25];
  const float* tW2   = (const float*)d_in[26];
  const float* tb2   = (const float*)d_in[27];

  float* out = (float*)d_out;
  float* ws  = (float*)d_ws;
  float* ctx  = ws;             // 512*320        = 163840 f
  float* P    = ws + 163840;    // 512*320
  float* Q    = ws + 327680;    // 512*320
  float* aggP = ws + 491520;    // 1024*320       = 327680 f
  float* hbuf = ws + 819200;    // 512*320  (total 983040 f = 3.93 MB)

  k_encoder<<<128, 256, 0, stream>>>(feat, attr, encW1, encb1, encW2, encb2, ctx);
  k_pq<<<128, 320, 0, stream>>>(ctx, edgW1, edgb1, P, Q);
  k_edge<<<1024, 320, 0, stream>>>(P, Q, pos, edgW1, edgW2, edgb2, aggP);
  k_gru<<<128, 320, 0, stream>>>(ctx, aggP, Wih, Whh, bih, bhh, hbuf);
  k_mode<<<512, 320, 0, stream>>>(hbuf, mW1, mb1, mW2, mb2, out);
  k_traj<<<dim3(128, 6), 320, 0, stream>>>(hbuf, tW1, tb1, tW2, tb2, out);
}

// Round 2
// 208.456 us; speedup vs baseline: 2.0873x; 2.0873x over previous
//
#include <hip/hip_runtime.h>

// ---------------------------------------------------------------------------
// Sizes: B=8, N=64, FD=128, HD=256, MD=64, D=320, NM=6, FS=80, rows=B*N=512
// ---------------------------------------------------------------------------

typedef __attribute__((ext_vector_type(8))) short bf16x8;   // 8 bf16 (4 VGPR)
typedef __attribute__((ext_vector_type(4))) float f32x4;

__device__ __forceinline__ unsigned short f2bf(float x) {   // RNE f32->bf16
  unsigned u = __float_as_uint(x);
  return (unsigned short)((u + 0x7fffu + ((u >> 16) & 1u)) >> 16);
}

// ---- JAX threefry2x32 (20 rounds), key = [0, 42] ---------------------------
__device__ __forceinline__ void threefry2x32(unsigned k0, unsigned k1,
                                             unsigned& x0, unsigned& x1) {
  const unsigned ks0 = k0, ks1 = k1, ks2 = k0 ^ k1 ^ 0x1BD11BDAu;
  x0 += ks0; x1 += ks1;
#define TFR(r) { x0 += x1; x1 = (x1 << (r)) | (x1 >> (32 - (r))); x1 ^= x0; }
  TFR(13) TFR(15) TFR(26) TFR(6)  x0 += ks1; x1 += ks2 + 1u;
  TFR(17) TFR(29) TFR(16) TFR(24) x0 += ks2; x1 += ks0 + 2u;
  TFR(13) TFR(15) TFR(26) TFR(6)  x0 += ks0; x1 += ks1 + 3u;
  TFR(17) TFR(29) TFR(16) TFR(24) x0 += ks1; x1 += ks2 + 4u;
  TFR(13) TFR(15) TFR(26) TFR(6)  x0 += ks2; x1 += ks0 + 5u;
#undef TFR
}

__device__ __forceinline__ float erfinv_xla(float x) {
  float w = -logf((1.0f - x) * (1.0f + x));
  float p;
  if (w < 5.0f) {
    w = w - 2.5f;
    p = 2.81022636e-08f;
    p = fmaf(p, w, 3.43273939e-07f);
    p = fmaf(p, w, -3.5233877e-06f);
    p = fmaf(p, w, -4.39150654e-06f);
    p = fmaf(p, w, 0.00021858087f);
    p = fmaf(p, w, -0.00125372503f);
    p = fmaf(p, w, -0.00417768164f);
    p = fmaf(p, w, 0.246640727f);
    p = fmaf(p, w, 1.50140941f);
  } else {
    w = sqrtf(w) - 3.0f;
    p = -0.000200214257f;
    p = fmaf(p, w, 0.000100950558f);
    p = fmaf(p, w, 0.00134934322f);
    p = fmaf(p, w, -0.00367342844f);
    p = fmaf(p, w, 0.00573950773f);
    p = fmaf(p, w, -0.0076224613f);
    p = fmaf(p, w, 0.00943887047f);
    p = fmaf(p, w, 1.00167406f);
    p = fmaf(p, w, 2.83297682f);
  }
  return p * x;
}

__device__ __forceinline__ float jax_normal42(unsigned idx) {
  unsigned x0 = 0u, x1 = idx;
  threefry2x32(0u, 42u, x0, x1);
  unsigned bits = x0 ^ x1;
  float f = __uint_as_float((bits >> 9) | 0x3f800000u) - 1.0f;
  const float lo = -0.99999994f;
  float u = fmaxf(lo, f * 2.0f + lo);
  return 1.41421356237f * erfinv_xla(u);
}

// ---------------------------------------------------------------------------
// K1: object encoder -> ctx[:,0:256]=emb ; ctx[:,256:320]=sampled
// ---------------------------------------------------------------------------
__global__ __launch_bounds__(256)
void k_encoder(const float* __restrict__ feat, const float* __restrict__ attr,
               const float* __restrict__ W1, const float* __restrict__ b1,
               const float* __restrict__ W2, const float* __restrict__ b2,
               float* __restrict__ ctx) {
  __shared__ float s_in[4][136];
  __shared__ float s_h1[4][256];
  const int r0 = blockIdx.x * 4;
  const int t = threadIdx.x;
  for (int r = 0; r < 4; ++r) {
    if (t < 128)      s_in[r][t] = feat[(r0 + r) * 128 + t];
    else if (t < 136) s_in[r][t] = attr[(r0 + r) * 8 + (t - 128)];
  }
  __syncthreads();
  float acc[4];
#pragma unroll
  for (int r = 0; r < 4; ++r) acc[r] = b1[t];
  for (int k = 0; k < 136; ++k) {
    const float w = W1[k * 256 + t];
#pragma unroll
    for (int r = 0; r < 4; ++r) acc[r] = fmaf(s_in[r][k], w, acc[r]);
  }
#pragma unroll
  for (int r = 0; r < 4; ++r) s_h1[r][t] = fmaxf(acc[r], 0.0f);
  __syncthreads();
#pragma unroll
  for (int r = 0; r < 4; ++r) acc[r] = b2[t];
  for (int k = 0; k < 256; ++k) {
    const float w = W2[k * 256 + t];
#pragma unroll
    for (int r = 0; r < 4; ++r) acc[r] = fmaf(s_h1[r][k], w, acc[r]);
  }
#pragma unroll
  for (int r = 0; r < 4; ++r) ctx[(r0 + r) * 320 + t] = fmaxf(acc[r], 0.0f);
  if (t < 64) {
    for (int r = 0; r < 4; ++r)
      ctx[(r0 + r) * 320 + 256 + t] = jax_normal42((unsigned)((r0 + r) * 64 + t));
  }
}

// ---------------------------------------------------------------------------
// K2: P = ctx @ W1[0:320] + b1 ; Q = ctx @ W1[320:640]
// ---------------------------------------------------------------------------
__global__ __launch_bounds__(320)
void k_pq(const float* __restrict__ ctx, const float* __restrict__ W1,
          const float* __restrict__ b1, float* __restrict__ P,
          float* __restrict__ Q) {
  __shared__ float s_c[4][320];
  const int r0 = blockIdx.x * 4;
  const int t = threadIdx.x;
#pragma unroll
  for (int r = 0; r < 4; ++r) s_c[r][t] = ctx[(r0 + r) * 320 + t];
  __syncthreads();
  float p[4], q[4];
#pragma unroll
  for (int r = 0; r < 4; ++r) { p[r] = b1[t]; q[r] = 0.0f; }
  for (int k = 0; k < 320; ++k) {
    const float wp = W1[k * 320 + t];
    const float wq = W1[(320 + k) * 320 + t];
#pragma unroll
    for (int r = 0; r < 4; ++r) {
      const float c = s_c[r][k];
      p[r] = fmaf(c, wp, p[r]);
      q[r] = fmaf(c, wq, q[r]);
    }
  }
#pragma unroll
  for (int r = 0; r < 4; ++r) {
    P[(r0 + r) * 320 + t] = p[r];
    Q[(r0 + r) * 320 + t] = q[r];
  }
}

// ---------------------------------------------------------------------------
// K_cvt: W2 f32 [320][320] -> bf16 fragment layout Bf[k>>3][n][k&7]
// grid 40, block 320.  Block g covers k = 8g..8g+7, thread = n.
// ---------------------------------------------------------------------------
__global__ __launch_bounds__(320)
void k_cvtW2(const float* __restrict__ W2, unsigned short* __restrict__ Bf) {
  const int g = blockIdx.x;   // k-octet
  const int n = threadIdx.x;
  unsigned short v[8];
#pragma unroll
  for (int e = 0; e < 8; ++e) v[e] = f2bf(W2[(g * 8 + e) * 320 + n]);
  ushort4* dst = (ushort4*)&Bf[(g * 320 + n) * 8];
  dst[0] = make_ushort4(v[0], v[1], v[2], v[3]);
  dst[1] = make_ushort4(v[4], v[5], v[6], v[7]);
}

// ---------------------------------------------------------------------------
// K3: edge MLP (layer1 rank-reduced + layer2 via MFMA) + masked mean, fused.
// grid 512 (one block per (b,i) row), block 256 = 4 waves.
// A = h1[64 j][320 k] (bf16, LDS, fragment layout [k>>3][j][k&7])
// B = W2 fragment-ready bf16 in global (L2-resident), C = e[64 j][320 n]
// epilogue: agg[row][n] = sum_{j!=i} relu(C + b2[n]) / 63
// wave w owns n-tiles {5w..5w+4} x all 4 m-tiles; acc[4][5] f32x4.
// ---------------------------------------------------------------------------
__global__ __launch_bounds__(256)
void k_edge(const float* __restrict__ P, const float* __restrict__ Q,
            const float* __restrict__ pos, const float* __restrict__ W1,
            const unsigned short* __restrict__ Bf, const float* __restrict__ b2,
            float* __restrict__ agg) {
  __shared__ __align__(16) unsigned short s_A[40 * 64 * 8];  // 40 KB
  const int bx = blockIdx.x;
  const int b = bx >> 6, i = bx & 63;
  const int t = threadIdx.x;
  const int w = t >> 6, l = t & 63;

  // ---- phase A: h1 -> s_A (bf16, fragment layout) ----
  {
    const int j = t & 63;          // edge's neighbor index
    const int sub = t >> 6;        // which k-octet quarter
    const float2 pi = *(const float2*)&pos[b * 128 + 2 * i];
    const float2 pj = *(const float2*)&pos[b * 128 + 2 * j];
    const float rx = pi.x - pj.x, ry = pi.y - pj.y;
    const float* __restrict__ Prow = P + bx * 320;
    const float* __restrict__ Qrow = Q + (b * 64 + j) * 320;
    const float* __restrict__ w0 = W1 + 640 * 320;
    const float* __restrict__ w1 = W1 + 641 * 320;
#pragma unroll
    for (int g = 0; g < 10; ++g) {
      const int k0 = g * 32 + sub * 8;
      const float4 p0 = *(const float4*)&Prow[k0];
      const float4 p1 = *(const float4*)&Prow[k0 + 4];
      const float4 q0 = *(const float4*)&Qrow[k0];
      const float4 q1 = *(const float4*)&Qrow[k0 + 4];
      const float4 a0 = *(const float4*)&w0[k0];
      const float4 a1 = *(const float4*)&w0[k0 + 4];
      const float4 c0 = *(const float4*)&w1[k0];
      const float4 c1 = *(const float4*)&w1[k0 + 4];
      float v[8];
      v[0] = fmaf(ry, c0.x, fmaf(rx, a0.x, p0.x + q0.x));
      v[1] = fmaf(ry, c0.y, fmaf(rx, a0.y, p0.y + q0.y));
      v[2] = fmaf(ry, c0.z, fmaf(rx, a0.z, p0.z + q0.z));
      v[3] = fmaf(ry, c0.w, fmaf(rx, a0.w, p0.w + q0.w));
      v[4] = fmaf(ry, c1.x, fmaf(rx, a1.x, p1.x + q1.x));
      v[5] = fmaf(ry, c1.y, fmaf(rx, a1.y, p1.y + q1.y));
      v[6] = fmaf(ry, c1.z, fmaf(rx, a1.z, p1.z + q1.z));
      v[7] = fmaf(ry, c1.w, fmaf(rx, a1.w, p1.w + q1.w));
      unsigned short u[8];
#pragma unroll
      for (int e = 0; e < 8; ++e) u[e] = f2bf(fmaxf(v[e], 0.0f));
      ushort4* dst = (ushort4*)&s_A[((g * 4 + sub) * 64 + j) * 8];
      dst[0] = make_ushort4(u[0], u[1], u[2], u[3]);
      dst[1] = make_ushort4(u[4], u[5], u[6], u[7]);
    }
  }
  __syncthreads();

  // ---- phase B: C = A @ B via MFMA ----
  f32x4 acc[4][5];
#pragma unroll
  for (int mt = 0; mt < 4; ++mt)
#pragma unroll
    for (int u = 0; u < 5; ++u) acc[mt][u] = (f32x4){0.f, 0.f, 0.f, 0.f};

  const int lg = l >> 4, lr = l & 15;              // lane group / lane row
  const unsigned short* __restrict__ Bbase = Bf + (lg * 320 + w * 80 + lr) * 8;
  const unsigned short* __restrict__ Abase = s_A + lg * 512 + lr * 8;

#pragma unroll 2
  for (int ks = 0; ks < 10; ++ks) {
    bf16x8 afr[4];
#pragma unroll
    for (int mt = 0; mt < 4; ++mt)
      afr[mt] = *(const bf16x8*)(Abase + ks * 2048 + mt * 128);
    bf16x8 bfr[5];
#pragma unroll
    for (int u = 0; u < 5; ++u)
      bfr[u] = *(const bf16x8*)(Bbase + ks * 10240 + u * 128);
#pragma unroll
    for (int mt = 0; mt < 4; ++mt)
#pragma unroll
      for (int u = 0; u < 5; ++u)
        acc[mt][u] = __builtin_amdgcn_mfma_f32_16x16x32_bf16(
            afr[mt], bfr[u], acc[mt][u], 0, 0, 0);
  }

  // ---- epilogue: +b2, relu, masked sum over j != i, /63 ----
#pragma unroll
  for (int u = 0; u < 5; ++u) {
    const int n = w * 80 + u * 16 + lr;
    const float bias = b2[n];
    float p = 0.0f;
#pragma unroll
    for (int mt = 0; mt < 4; ++mt) {
#pragma unroll
      for (int r = 0; r < 4; ++r) {
        const int j = mt * 16 + lg * 4 + r;
        const float e = fmaxf(acc[mt][u][r] + bias, 0.0f);
        p += (j != i) ? e : 0.0f;
      }
    }
    p += __shfl_xor(p, 16);
    p += __shfl_xor(p, 32);
    if (l < 16) agg[bx * 320 + n] = p * (1.0f / 63.0f);
  }
}

// ---------------------------------------------------------------------------
// K4: GRUCell.  grid 128, block 320 (4 rows/block)
// ---------------------------------------------------------------------------
__global__ __launch_bounds__(320)
void k_gru(const float* __restrict__ ctx, const float* __restrict__ agg,
           const float* __restrict__ Wih, const float* __restrict__ Whh,
           const float* __restrict__ bih, const float* __restrict__ bhh,
           float* __restrict__ h) {
  __shared__ float s_x[4][640];
  const int r0 = blockIdx.x * 4;
  const int t = threadIdx.x;
  float cself[4];
#pragma unroll
  for (int r = 0; r < 4; ++r) {
    const int row = r0 + r;
    const float c = ctx[row * 320 + t];
    cself[r] = c;
    s_x[r][t] = c;
    s_x[r][320 + t] = agg[row * 320 + t];
  }
  __syncthreads();
  float gr[4], gz[4], gn[4];
#pragma unroll
  for (int r = 0; r < 4; ++r) { gr[r] = bih[t]; gz[r] = bih[320 + t]; gn[r] = bih[640 + t]; }
  for (int k = 0; k < 640; ++k) {
    const float wr = Wih[k * 960 + t];
    const float wz = Wih[k * 960 + 320 + t];
    const float wn = Wih[k * 960 + 640 + t];
#pragma unroll
    for (int r = 0; r < 4; ++r) {
      const float x = s_x[r][k];
      gr[r] = fmaf(x, wr, gr[r]);
      gz[r] = fmaf(x, wz, gz[r]);
      gn[r] = fmaf(x, wn, gn[r]);
    }
  }
  float hr[4], hz[4], hn[4];
#pragma unroll
  for (int r = 0; r < 4; ++r) { hr[r] = bhh[t]; hz[r] = bhh[320 + t]; hn[r] = bhh[640 + t]; }
  for (int k = 0; k < 320; ++k) {
    const float wr = Whh[k * 960 + t];
    const float wz = Whh[k * 960 + 320 + t];
    const float wn = Whh[k * 960 + 640 + t];
#pragma unroll
    for (int r = 0; r < 4; ++r) {
      const float x = s_x[r][k];
      hr[r] = fmaf(x, wr, hr[r]);
      hz[r] = fmaf(x, wz, hz[r]);
      hn[r] = fmaf(x, wn, hn[r]);
    }
  }
#pragma unroll
  for (int r = 0; r < 4; ++r) {
    const float rr = 1.0f / (1.0f + expf(-(gr[r] + hr[r])));
    const float zz = 1.0f / (1.0f + expf(-(gz[r] + hz[r])));
    const float nn = tanhf(fmaf(rr, hn[r], gn[r]));
    h[(r0 + r) * 320 + t] = (1.0f - zz) * nn + zz * cself[r];
  }
}

// ---------------------------------------------------------------------------
// K5a: mode head + softmax.  grid 512, block 320
// ---------------------------------------------------------------------------
__global__ __launch_bounds__(320)
void k_mode(const float* __restrict__ h, const float* __restrict__ W1,
            const float* __restrict__ b1, const float* __restrict__ W2,
            const float* __restrict__ b2, float* __restrict__ out) {
  __shared__ float s_h[320];
  __shared__ float s_m[320];
  __shared__ float s_l[6];
  const int row = blockIdx.x;
  const int t = threadIdx.x;
  s_h[t] = h[row * 320 + t];
  __syncthreads();
  float a = b1[t];
  for (int k = 0; k < 320; ++k) a = fmaf(s_h[k], W1[k * 320 + t], a);
  s_m[t] = fmaxf(a, 0.0f);
  __syncthreads();
  if (t < 6) {
    float l = b2[t];
    for (int k = 0; k < 320; ++k) l = fmaf(s_m[k], W2[k * 6 + t], l);
    s_l[t] = l;
  }
  __syncthreads();
  if (t < 6) {
    float mx = s_l[0];
#pragma unroll
    for (int q = 1; q < 6; ++q) mx = fmaxf(mx, s_l[q]);
    float sum = 0.0f;
#pragma unroll
    for (int q = 0; q < 6; ++q) sum += expf(s_l[q] - mx);
    out[491520 + row * 6 + t] = expf(s_l[t] - mx) / sum;
  }
}

// ---------------------------------------------------------------------------
// K5b: trajectory head.  grid (128, 6), block 320 (4 rows/block)
// ---------------------------------------------------------------------------
__global__ __launch_bounds__(320)
void k_traj(const float* __restrict__ h, const float* __restrict__ W1,
            const float* __restrict__ b1, const float* __restrict__ W2,
            const float* __restrict__ b2, float* __restrict__ out) {
  __shared__ float s_h[4][320];
  __shared__ float s_t[4][320];
  const int r0 = blockIdx.x * 4;
  const int m = blockIdx.y;
  const int t = threadIdx.x;
#pragma unroll
  for (int r = 0; r < 4; ++r) s_h[r][t] = h[(r0 + r) * 320 + t];
  __syncthreads();
  float acc[4];
#pragma unroll
  for (int r = 0; r < 4; ++r) acc[r] = b1[m * 320 + t];
  const float* w1 = W1 + m * 320 * 320;
  for (int k = 0; k < 320; ++k) {
    const float w = w1[k * 320 + t];
#pragma unroll
    for (int r = 0; r < 4; ++r) acc[r] = fmaf(s_h[r][k], w, acc[r]);
  }
#pragma unroll
  for (int r = 0; r < 4; ++r) s_t[r][t] = fmaxf(acc[r], 0.0f);
  __syncthreads();
  if (t < 160) {
    float o[4];
#pragma unroll
    for (int r = 0; r < 4; ++r) o[r] = b2[m * 160 + t];
    const float* w2 = W2 + m * 320 * 160;
    for (int k = 0; k < 320; ++k) {
      const float w = w2[k * 160 + t];
#pragma unroll
      for (int r = 0; r < 4; ++r) o[r] = fmaf(s_t[r][k], w, o[r]);
    }
#pragma unroll
    for (int r = 0; r < 4; ++r) out[((r0 + r) * 6 + m) * 160 + t] = o[r];
  }
}

// ---------------------------------------------------------------------------
extern "C" void kernel_launch(void* const* d_in, const int* in_sizes, int n_in,
                              void* d_out, int out_size, void* d_ws, size_t ws_size,
                              hipStream_t stream) {
  (void)in_sizes; (void)n_in; (void)out_size; (void)ws_size;
  const float* feat  = (const float*)d_in[0];
  const float* attr  = (const float*)d_in[1];
  const float* pos   = (const float*)d_in[3];
  const float* encW1 = (const float*)d_in[4];
  const float* encb1 = (const float*)d_in[5];
  const float* encW2 = (const float*)d_in[6];
  const float* encb2 = (const float*)d_in[7];
  const float* edgW1 = (const float*)d_in[12];
  const float* edgb1 = (const float*)d_in[13];
  const float* edgW2 = (const float*)d_in[14];
  const float* edgb2 = (const float*)d_in[15];
  const float* Wih   = (const float*)d_in[16];
  const float* Whh   = (const float*)d_in[17];
  const float* bih   = (const float*)d_in[18];
  const float* bhh   = (const float*)d_in[19];
  const float* mW1   = (const float*)d_in[20];
  const float* mb1   = (const float*)d_in[21];
  const float* mW2   = (const float*)d_in[22];
  const float* mb2   = (const float*)d_in[23];
  const float* tW1   = (const float*)d_in[24];
  const float* tb1   = (const float*)d_in[25];
  const float* tW2   = (const float*)d_in[26];
  const float* tb2   = (const float*)d_in[27];

  float* out = (float*)d_out;
  float* ws  = (float*)d_ws;
  float* ctx  = ws;                       // 512*320
  float* P    = ws + 163840;              // 512*320
  float* Q    = ws + 327680;              // 512*320
  float* agg  = ws + 491520;              // 512*320
  float* hbuf = ws + 655360;              // 512*320
  unsigned short* W2bf = (unsigned short*)(ws + 819200);  // 320*320 bf16

  k_encoder<<<128, 256, 0, stream>>>(feat, attr, encW1, encb1, encW2, encb2, ctx);
  k_cvtW2<<<40, 320, 0, stream>>>(edgW2, W2bf);
  k_pq<<<128, 320, 0, stream>>>(ctx, edgW1, edgb1, P, Q);
  k_edge<<<512, 256, 0, stream>>>(P, Q, pos, edgW1, W2bf, edgb2, agg);
  k_gru<<<128, 320, 0, stream>>>(ctx, agg, Wih, Whh, bih, bhh, hbuf);
  k_mode<<<512, 320, 0, stream>>>(hbuf, mW1, mb1, mW2, mb2, out);
  k_traj<<<dim3(128, 6), 320, 0, stream>>>(hbuf, tW1, tb1, tW2, tb2, out);
}

// Round 3
// 208.313 us; speedup vs baseline: 2.0888x; 1.0007x over previous
//
#include <hip/hip_runtime.h>

// ---------------------------------------------------------------------------
// Sizes: B=8, N=64, FD=128, HD=256, MD=64, D=320, NM=6, FS=80, rows=B*N=512
// ---------------------------------------------------------------------------

typedef __attribute__((ext_vector_type(8))) short bf16x8;   // 8 bf16 (4 VGPR)
typedef __attribute__((ext_vector_type(4))) float f32x4;

__device__ __forceinline__ unsigned short f2bf(float x) {   // RNE f32->bf16
  unsigned u = __float_as_uint(x);
  return (unsigned short)((u + 0x7fffu + ((u >> 16) & 1u)) >> 16);
}

// ---- JAX threefry2x32 (20 rounds), key = [0, 42] ---------------------------
__device__ __forceinline__ void threefry2x32(unsigned k0, unsigned k1,
                                             unsigned& x0, unsigned& x1) {
  const unsigned ks0 = k0, ks1 = k1, ks2 = k0 ^ k1 ^ 0x1BD11BDAu;
  x0 += ks0; x1 += ks1;
#define TFR(r) { x0 += x1; x1 = (x1 << (r)) | (x1 >> (32 - (r))); x1 ^= x0; }
  TFR(13) TFR(15) TFR(26) TFR(6)  x0 += ks1; x1 += ks2 + 1u;
  TFR(17) TFR(29) TFR(16) TFR(24) x0 += ks2; x1 += ks0 + 2u;
  TFR(13) TFR(15) TFR(26) TFR(6)  x0 += ks0; x1 += ks1 + 3u;
  TFR(17) TFR(29) TFR(16) TFR(24) x0 += ks1; x1 += ks2 + 4u;
  TFR(13) TFR(15) TFR(26) TFR(6)  x0 += ks2; x1 += ks0 + 5u;
#undef TFR
}

__device__ __forceinline__ float erfinv_xla(float x) {
  float w = -logf((1.0f - x) * (1.0f + x));
  float p;
  if (w < 5.0f) {
    w = w - 2.5f;
    p = 2.81022636e-08f;
    p = fmaf(p, w, 3.43273939e-07f);
    p = fmaf(p, w, -3.5233877e-06f);
    p = fmaf(p, w, -4.39150654e-06f);
    p = fmaf(p, w, 0.00021858087f);
    p = fmaf(p, w, -0.00125372503f);
    p = fmaf(p, w, -0.00417768164f);
    p = fmaf(p, w, 0.246640727f);
    p = fmaf(p, w, 1.50140941f);
  } else {
    w = sqrtf(w) - 3.0f;
    p = -0.000200214257f;
    p = fmaf(p, w, 0.000100950558f);
    p = fmaf(p, w, 0.00134934322f);
    p = fmaf(p, w, -0.00367342844f);
    p = fmaf(p, w, 0.00573950773f);
    p = fmaf(p, w, -0.0076224613f);
    p = fmaf(p, w, 0.00943887047f);
    p = fmaf(p, w, 1.00167406f);
    p = fmaf(p, w, 2.83297682f);
  }
  return p * x;
}

__device__ __forceinline__ float jax_normal42(unsigned idx) {
  unsigned x0 = 0u, x1 = idx;
  threefry2x32(0u, 42u, x0, x1);
  unsigned bits = x0 ^ x1;
  float f = __uint_as_float((bits >> 9) | 0x3f800000u) - 1.0f;
  const float lo = -0.99999994f;
  float u = fmaxf(lo, f * 2.0f + lo);
  return 1.41421356237f * erfinv_xla(u);
}

// ---------------------------------------------------------------------------
// K0: fused weight converter f32 -> bf16 fragment layout [k>>3][n][k&7].
// Flat octet id over 5 jobs; grid 950, block 256 (243200 octets total).
// ---------------------------------------------------------------------------
__global__ __launch_bounds__(256)
void k_cvt(const float* __restrict__ W2e, const float* __restrict__ Wih,
           const float* __restrict__ Whh, const float* __restrict__ T1,
           const float* __restrict__ T2, unsigned short* __restrict__ ub) {
  const int id = blockIdx.x * 256 + threadIdx.x;
  const float* src;
  unsigned short* dst;
  int rem, N;
  if (id < 12800)       { src = W2e; dst = ub;           rem = id;          N = 320; }
  else if (id < 89600)  { src = Wih; dst = ub + 102400;  rem = id - 12800;  N = 960; }
  else if (id < 128000) { src = Whh; dst = ub + 716800;  rem = id - 89600;  N = 960; }
  else if (id < 204800) { src = T1;  dst = ub + 1024000; rem = id - 128000; N = 320; }
  else                  { src = T2;  dst = ub + 1638400; rem = id - 204800; N = 160; }
  const int g = rem / N, n = rem - g * N;
  const float* s = src + g * 8 * N + n;
  unsigned short v[8];
#pragma unroll
  for (int e = 0; e < 8; ++e) v[e] = f2bf(s[e * N]);
  ushort4* d = (ushort4*)&dst[(size_t)rem * 8];
  d[0] = make_ushort4(v[0], v[1], v[2], v[3]);
  d[1] = make_ushort4(v[4], v[5], v[6], v[7]);
}

// ---------------------------------------------------------------------------
// K1: object encoder -> ctx[:,0:256]=emb ; ctx[:,256:320]=sampled
// ---------------------------------------------------------------------------
__global__ __launch_bounds__(256)
void k_encoder(const float* __restrict__ feat, const float* __restrict__ attr,
               const float* __restrict__ W1, const float* __restrict__ b1,
               const float* __restrict__ W2, const float* __restrict__ b2,
               float* __restrict__ ctx) {
  __shared__ float s_in[4][136];
  __shared__ float s_h1[4][256];
  const int r0 = blockIdx.x * 4;
  const int t = threadIdx.x;
  for (int r = 0; r < 4; ++r) {
    if (t < 128)      s_in[r][t] = feat[(r0 + r) * 128 + t];
    else if (t < 136) s_in[r][t] = attr[(r0 + r) * 8 + (t - 128)];
  }
  __syncthreads();
  float acc[4];
#pragma unroll
  for (int r = 0; r < 4; ++r) acc[r] = b1[t];
  for (int k = 0; k < 136; ++k) {
    const float w = W1[k * 256 + t];
#pragma unroll
    for (int r = 0; r < 4; ++r) acc[r] = fmaf(s_in[r][k], w, acc[r]);
  }
#pragma unroll
  for (int r = 0; r < 4; ++r) s_h1[r][t] = fmaxf(acc[r], 0.0f);
  __syncthreads();
#pragma unroll
  for (int r = 0; r < 4; ++r) acc[r] = b2[t];
  for (int k = 0; k < 256; ++k) {
    const float w = W2[k * 256 + t];
#pragma unroll
    for (int r = 0; r < 4; ++r) acc[r] = fmaf(s_h1[r][k], w, acc[r]);
  }
#pragma unroll
  for (int r = 0; r < 4; ++r) ctx[(r0 + r) * 320 + t] = fmaxf(acc[r], 0.0f);
  if (t < 64) {
    for (int r = 0; r < 4; ++r)
      ctx[(r0 + r) * 320 + 256 + t] = jax_normal42((unsigned)((r0 + r) * 64 + t));
  }
}

// ---------------------------------------------------------------------------
// K2: P = ctx @ W1[0:320] + b1 ; Q = ctx @ W1[320:640]
// ---------------------------------------------------------------------------
__global__ __launch_bounds__(320)
void k_pq(const float* __restrict__ ctx, const float* __restrict__ W1,
          const float* __restrict__ b1, float* __restrict__ P,
          float* __restrict__ Q) {
  __shared__ float s_c[4][320];
  const int r0 = blockIdx.x * 4;
  const int t = threadIdx.x;
#pragma unroll
  for (int r = 0; r < 4; ++r) s_c[r][t] = ctx[(r0 + r) * 320 + t];
  __syncthreads();
  float p[4], q[4];
#pragma unroll
  for (int r = 0; r < 4; ++r) { p[r] = b1[t]; q[r] = 0.0f; }
  for (int k = 0; k < 320; ++k) {
    const float wp = W1[k * 320 + t];
    const float wq = W1[(320 + k) * 320 + t];
#pragma unroll
    for (int r = 0; r < 4; ++r) {
      const float c = s_c[r][k];
      p[r] = fmaf(c, wp, p[r]);
      q[r] = fmaf(c, wq, q[r]);
    }
  }
#pragma unroll
  for (int r = 0; r < 4; ++r) {
    P[(r0 + r) * 320 + t] = p[r];
    Q[(r0 + r) * 320 + t] = q[r];
  }
}

// ---------------------------------------------------------------------------
// K3: edge MLP (layer1 rank-reduced + layer2 via MFMA) + masked mean, fused.
// grid 512 (one block per (b,i)), block 256 = 4 waves.
// ---------------------------------------------------------------------------
__global__ __launch_bounds__(256)
void k_edge(const float* __restrict__ P, const float* __restrict__ Q,
            const float* __restrict__ pos, const float* __restrict__ W1,
            const unsigned short* __restrict__ Bf, const float* __restrict__ b2,
            float* __restrict__ agg) {
  __shared__ __align__(16) unsigned short s_A[40 * 64 * 8];  // 40 KB
  const int bx = blockIdx.x;
  const int b = bx >> 6, i = bx & 63;
  const int t = threadIdx.x;
  const int w = t >> 6, l = t & 63;

  {
    const int j = t & 63;
    const int sub = t >> 6;
    const float2 pi = *(const float2*)&pos[b * 128 + 2 * i];
    const float2 pj = *(const float2*)&pos[b * 128 + 2 * j];
    const float rx = pi.x - pj.x, ry = pi.y - pj.y;
    const float* __restrict__ Prow = P + bx * 320;
    const float* __restrict__ Qrow = Q + (b * 64 + j) * 320;
    const float* __restrict__ w0 = W1 + 640 * 320;
    const float* __restrict__ w1 = W1 + 641 * 320;
#pragma unroll
    for (int g = 0; g < 10; ++g) {
      const int k0 = g * 32 + sub * 8;
      const float4 p0 = *(const float4*)&Prow[k0];
      const float4 p1 = *(const float4*)&Prow[k0 + 4];
      const float4 q0 = *(const float4*)&Qrow[k0];
      const float4 q1 = *(const float4*)&Qrow[k0 + 4];
      const float4 a0 = *(const float4*)&w0[k0];
      const float4 a1 = *(const float4*)&w0[k0 + 4];
      const float4 c0 = *(const float4*)&w1[k0];
      const float4 c1 = *(const float4*)&w1[k0 + 4];
      float v[8];
      v[0] = fmaf(ry, c0.x, fmaf(rx, a0.x, p0.x + q0.x));
      v[1] = fmaf(ry, c0.y, fmaf(rx, a0.y, p0.y + q0.y));
      v[2] = fmaf(ry, c0.z, fmaf(rx, a0.z, p0.z + q0.z));
      v[3] = fmaf(ry, c0.w, fmaf(rx, a0.w, p0.w + q0.w));
      v[4] = fmaf(ry, c1.x, fmaf(rx, a1.x, p1.x + q1.x));
      v[5] = fmaf(ry, c1.y, fmaf(rx, a1.y, p1.y + q1.y));
      v[6] = fmaf(ry, c1.z, fmaf(rx, a1.z, p1.z + q1.z));
      v[7] = fmaf(ry, c1.w, fmaf(rx, a1.w, p1.w + q1.w));
      unsigned short u[8];
#pragma unroll
      for (int e = 0; e < 8; ++e) u[e] = f2bf(fmaxf(v[e], 0.0f));
      ushort4* dst = (ushort4*)&s_A[((g * 4 + sub) * 64 + j) * 8];
      dst[0] = make_ushort4(u[0], u[1], u[2], u[3]);
      dst[1] = make_ushort4(u[4], u[5], u[6], u[7]);
    }
  }
  __syncthreads();

  f32x4 acc[4][5];
#pragma unroll
  for (int mt = 0; mt < 4; ++mt)
#pragma unroll
    for (int u = 0; u < 5; ++u) acc[mt][u] = (f32x4){0.f, 0.f, 0.f, 0.f};

  const int lg = l >> 4, lr = l & 15;
  const unsigned short* __restrict__ Bbase = Bf + (lg * 320 + w * 80 + lr) * 8;
  const unsigned short* __restrict__ Abase = s_A + lg * 512 + lr * 8;

#pragma unroll 2
  for (int ks = 0; ks < 10; ++ks) {
    bf16x8 afr[4];
#pragma unroll
    for (int mt = 0; mt < 4; ++mt)
      afr[mt] = *(const bf16x8*)(Abase + ks * 2048 + mt * 128);
    bf16x8 bfr[5];
#pragma unroll
    for (int u = 0; u < 5; ++u)
      bfr[u] = *(const bf16x8*)(Bbase + ks * 10240 + u * 128);
#pragma unroll
    for (int mt = 0; mt < 4; ++mt)
#pragma unroll
      for (int u = 0; u < 5; ++u)
        acc[mt][u] = __builtin_amdgcn_mfma_f32_16x16x32_bf16(
            afr[mt], bfr[u], acc[mt][u], 0, 0, 0);
  }

#pragma unroll
  for (int u = 0; u < 5; ++u) {
    const int n = w * 80 + u * 16 + lr;
    const float bias = b2[n];
    float p = 0.0f;
#pragma unroll
    for (int mt = 0; mt < 4; ++mt) {
#pragma unroll
      for (int r = 0; r < 4; ++r) {
        const int j = mt * 16 + lg * 4 + r;
        const float e = fmaxf(acc[mt][u][r] + bias, 0.0f);
        p += (j != i) ? e : 0.0f;
      }
    }
    p += __shfl_xor(p, 16);
    p += __shfl_xor(p, 32);
    if (l < 16) agg[bx * 320 + n] = p * (1.0f / 63.0f);
  }
}

// ---------------------------------------------------------------------------
// K4: GRUCell via MFMA, fused pointwise.
// grid 80 = (row-block 16) x (d-block 5); block 256 = 4 waves.
// Block: rows [rb*32, +32), d-cols [db*64, +64); wave w owns d-sub [w*16,+16)
// and all 3 gate columns for both gi (K=640) and gh (K=320).
// ---------------------------------------------------------------------------
__global__ __launch_bounds__(256)
void k_gruM(const float* __restrict__ ctx, const float* __restrict__ agg,
            const unsigned short* __restrict__ BfI,
            const unsigned short* __restrict__ BfH,
            const float* __restrict__ bih, const float* __restrict__ bhh,
            float* __restrict__ h) {
  __shared__ __align__(16) unsigned short s_x[80 * 32 * 8];  // 40 KB
  const int rb = blockIdx.x / 5, db = blockIdx.x % 5;
  const int row0 = rb * 32, d0 = db * 64;
  const int t = threadIdx.x;

  // phase A: x = [ctx | agg] rows row0..row0+31 -> bf16 fragment layout
  {
    const int r = t >> 3, ob = t & 7;
    const int row = row0 + r;
#pragma unroll
    for (int it = 0; it < 10; ++it) {
      const int oct = ob + it * 8;  // 0..79
      float4 v0, v1;
      if (oct < 40) {
        v0 = *(const float4*)&ctx[row * 320 + oct * 8];
        v1 = *(const float4*)&ctx[row * 320 + oct * 8 + 4];
      } else {
        v0 = *(const float4*)&agg[row * 320 + (oct - 40) * 8];
        v1 = *(const float4*)&agg[row * 320 + (oct - 40) * 8 + 4];
      }
      ushort4* dst = (ushort4*)&s_x[(oct * 32 + r) * 8];
      dst[0] = make_ushort4(f2bf(v0.x), f2bf(v0.y), f2bf(v0.z), f2bf(v0.w));
      dst[1] = make_ushort4(f2bf(v1.x), f2bf(v1.y), f2bf(v1.z), f2bf(v1.w));
    }
  }
  __syncthreads();

  const int w = t >> 6, l = t & 63, lg = l >> 4, lr = l & 15;
  const int d = d0 + w * 16 + lr;

  f32x4 accI[2][3], accH[2][3];
#pragma unroll
  for (int mt = 0; mt < 2; ++mt)
#pragma unroll
    for (int g = 0; g < 3; ++g) {
      accI[mt][g] = (f32x4){0.f, 0.f, 0.f, 0.f};
      accH[mt][g] = (f32x4){0.f, 0.f, 0.f, 0.f};
    }

  // gi: K=640 (20 k-steps)
#pragma unroll 2
  for (int ks = 0; ks < 20; ++ks) {
    bf16x8 afr[2];
#pragma unroll
    for (int mt = 0; mt < 2; ++mt)
      afr[mt] = *(const bf16x8*)&s_x[(((ks * 4 + lg) * 32) + mt * 16 + lr) * 8];
    bf16x8 bfr[3];
#pragma unroll
    for (int g = 0; g < 3; ++g)
      bfr[g] = *(const bf16x8*)&BfI[((ks * 4 + lg) * 960 + g * 320 + d) * 8];
#pragma unroll
    for (int mt = 0; mt < 2; ++mt)
#pragma unroll
      for (int g = 0; g < 3; ++g)
        accI[mt][g] = __builtin_amdgcn_mfma_f32_16x16x32_bf16(
            afr[mt], bfr[g], accI[mt][g], 0, 0, 0);
  }
  // gh: K=320 (10 k-steps), A = ctx part of s_x
#pragma unroll 2
  for (int ks = 0; ks < 10; ++ks) {
    bf16x8 afr[2];
#pragma unroll
    for (int mt = 0; mt < 2; ++mt)
      afr[mt] = *(const bf16x8*)&s_x[(((ks * 4 + lg) * 32) + mt * 16 + lr) * 8];
    bf16x8 bfr[3];
#pragma unroll
    for (int g = 0; g < 3; ++g)
      bfr[g] = *(const bf16x8*)&BfH[((ks * 4 + lg) * 960 + g * 320 + d) * 8];
#pragma unroll
    for (int mt = 0; mt < 2; ++mt)
#pragma unroll
      for (int g = 0; g < 3; ++g)
        accH[mt][g] = __builtin_amdgcn_mfma_f32_16x16x32_bf16(
            afr[mt], bfr[g], accH[mt][g], 0, 0, 0);
  }

  const float b_ir = bih[d], b_iz = bih[320 + d], b_in = bih[640 + d];
  const float b_hr = bhh[d], b_hz = bhh[320 + d], b_hn = bhh[640 + d];
#pragma unroll
  for (int mt = 0; mt < 2; ++mt) {
#pragma unroll
    for (int r = 0; r < 4; ++r) {
      const int row = row0 + mt * 16 + lg * 4 + r;
      const float ir = accI[mt][0][r] + b_ir;
      const float iz = accI[mt][1][r] + b_iz;
      const float inn = accI[mt][2][r] + b_in;
      const float hr = accH[mt][0][r] + b_hr;
      const float hz = accH[mt][1][r] + b_hz;
      const float hn = accH[mt][2][r] + b_hn;
      const float rr = 1.0f / (1.0f + expf(-(ir + hr)));
      const float zz = 1.0f / (1.0f + expf(-(iz + hz)));
      const float nn = tanhf(fmaf(rr, hn, inn));
      const float c = ctx[row * 320 + d];
      h[row * 320 + d] = (1.0f - zz) * nn + zz * c;
    }
  }
}

// ---------------------------------------------------------------------------
// K5a: mode head + softmax.  grid 512, block 320
// ---------------------------------------------------------------------------
__global__ __launch_bounds__(320)
void k_mode(const float* __restrict__ h, const float* __restrict__ W1,
            const float* __restrict__ b1, const float* __restrict__ W2,
            const float* __restrict__ b2, float* __restrict__ out) {
  __shared__ float s_h[320];
  __shared__ float s_m[320];
  __shared__ float s_l[6];
  const int row = blockIdx.x;
  const int t = threadIdx.x;
  s_h[t] = h[row * 320 + t];
  __syncthreads();
  float a = b1[t];
  for (int k = 0; k < 320; ++k) a = fmaf(s_h[k], W1[k * 320 + t], a);
  s_m[t] = fmaxf(a, 0.0f);
  __syncthreads();
  if (t < 6) {
    float l = b2[t];
    for (int k = 0; k < 320; ++k) l = fmaf(s_m[k], W2[k * 6 + t], l);
    s_l[t] = l;
  }
  __syncthreads();
  if (t < 6) {
    float mx = s_l[0];
#pragma unroll
    for (int q = 1; q < 6; ++q) mx = fmaxf(mx, s_l[q]);
    float sum = 0.0f;
#pragma unroll
    for (int q = 0; q < 6; ++q) sum += expf(s_l[q] - mx);
    out[491520 + row * 6 + t] = expf(s_l[t] - mx) / sum;
  }
}

// ---------------------------------------------------------------------------
// K5b: trajectory head via MFMA, both GEMMs fused.
// grid (16, 6); block 256 = 4 waves. Block: rows [rb*32,+32), mode m.
// GEMM1: t=relu(h@W1_m+b1_m) [32,320]; GEMM2: out=t@W2_m+b2_m [32,160].
// ---------------------------------------------------------------------------
__global__ __launch_bounds__(256)
void k_trajM(const float* __restrict__ h, const unsigned short* __restrict__ B1,
             const float* __restrict__ b1, const unsigned short* __restrict__ B2,
             const float* __restrict__ b2, float* __restrict__ out) {
  __shared__ __align__(16) unsigned short s_h[40 * 32 * 8];  // 20 KB
  __shared__ __align__(16) unsigned short s_t[40 * 32 * 8];  // 20 KB
  const int rb = blockIdx.x, m = blockIdx.y;
  const int row0 = rb * 32;
  const int t = threadIdx.x;

  // stage h rows -> bf16 fragment layout
  {
    const int r = t >> 3, ob = t & 7;
    const int row = row0 + r;
#pragma unroll
    for (int it = 0; it < 5; ++it) {
      const int oct = ob + it * 8;  // 0..39
      const float4 v0 = *(const float4*)&h[row * 320 + oct * 8];
      const float4 v1 = *(const float4*)&h[row * 320 + oct * 8 + 4];
      ushort4* dst = (ushort4*)&s_h[(oct * 32 + r) * 8];
      dst[0] = make_ushort4(f2bf(v0.x), f2bf(v0.y), f2bf(v0.z), f2bf(v0.w));
      dst[1] = make_ushort4(f2bf(v1.x), f2bf(v1.y), f2bf(v1.z), f2bf(v1.w));
    }
  }
  __syncthreads();

  const int w = t >> 6, l = t & 63, lg = l >> 4, lr = l & 15;

  // GEMM1: N=320, wave w -> n = w*80 + u*16 + lr
  f32x4 acc1[2][5];
#pragma unroll
  for (int mt = 0; mt < 2; ++mt)
#pragma unroll
    for (int u = 0; u < 5; ++u) acc1[mt][u] = (f32x4){0.f, 0.f, 0.f, 0.f};
  const unsigned short* __restrict__ B1m = B1 + m * 102400;
#pragma unroll 2
  for (int ks = 0; ks < 10; ++ks) {
    bf16x8 afr[2];
#pragma unroll
    for (int mt = 0; mt < 2; ++mt)
      afr[mt] = *(const bf16x8*)&s_h[(((ks * 4 + lg) * 32) + mt * 16 + lr) * 8];
    bf16x8 bfr[5];
#pragma unroll
    for (int u = 0; u < 5; ++u)
      bfr[u] = *(const bf16x8*)&B1m[((ks * 4 + lg) * 320 + w * 80 + u * 16 + lr) * 8];
#pragma unroll
    for (int mt = 0; mt < 2; ++mt)
#pragma unroll
      for (int u = 0; u < 5; ++u)
        acc1[mt][u] = __builtin_amdgcn_mfma_f32_16x16x32_bf16(
            afr[mt], bfr[u], acc1[mt][u], 0, 0, 0);
  }
  // epilogue1: relu(+b1) -> s_t (fragment layout, b16 scatter)
#pragma unroll
  for (int u = 0; u < 5; ++u) {
    const int n = w * 80 + u * 16 + lr;
    const float bias = b1[m * 320 + n];
#pragma unroll
    for (int mt = 0; mt < 2; ++mt) {
#pragma unroll
      for (int r = 0; r < 4; ++r) {
        const int row = mt * 16 + lg * 4 + r;
        s_t[((n >> 3) * 32 + row) * 8 + (n & 7)] =
            f2bf(fmaxf(acc1[mt][u][r] + bias, 0.0f));
      }
    }
  }
  __syncthreads();

  // GEMM2: N=160, 10 n-tiles split {3,2,3,2} across waves
  const int cnt = (w == 0 || w == 2) ? 3 : 2;
  const int nb = (w == 0) ? 0 : (w == 1) ? 3 : (w == 2) ? 5 : 8;
  f32x4 acc2[2][3];
#pragma unroll
  for (int mt = 0; mt < 2; ++mt)
#pragma unroll
    for (int u = 0; u < 3; ++u) acc2[mt][u] = (f32x4){0.f, 0.f, 0.f, 0.f};
  const unsigned short* __restrict__ B2m = B2 + m * 51200;
#pragma unroll 2
  for (int ks = 0; ks < 10; ++ks) {
    bf16x8 afr[2];
#pragma unroll
    for (int mt = 0; mt < 2; ++mt)
      afr[mt] = *(const bf16x8*)&s_t[(((ks * 4 + lg) * 32) + mt * 16 + lr) * 8];
    bf16x8 bfr[3];
    for (int u = 0; u < cnt; ++u)
      bfr[u] = *(const bf16x8*)&B2m[((ks * 4 + lg) * 160 + (nb + u) * 16 + lr) * 8];
    for (int u = 0; u < cnt; ++u)
#pragma unroll
      for (int mt = 0; mt < 2; ++mt)
        acc2[mt][u] = __builtin_amdgcn_mfma_f32_16x16x32_bf16(
            afr[mt], bfr[u], acc2[mt][u], 0, 0, 0);
  }
  for (int u = 0; u < cnt; ++u) {
    const int n = (nb + u) * 16 + lr;
    const float bias = b2[m * 160 + n];
#pragma unroll
    for (int mt = 0; mt < 2; ++mt) {
#pragma unroll
      for (int r = 0; r < 4; ++r) {
        const int row = row0 + mt * 16 + lg * 4 + r;
        out[(row * 6 + m) * 160 + n] = acc2[mt][u][r] + bias;
      }
    }
  }
}

// ---------------------------------------------------------------------------
extern "C" void kernel_launch(void* const* d_in, const int* in_sizes, int n_in,
                              void* d_out, int out_size, void* d_ws, size_t ws_size,
                              hipStream_t stream) {
  (void)in_sizes; (void)n_in; (void)out_size; (void)ws_size;
  const float* feat  = (const float*)d_in[0];
  const float* attr  = (const float*)d_in[1];
  const float* pos   = (const float*)d_in[3];
  const float* encW1 = (const float*)d_in[4];
  const float* encb1 = (const float*)d_in[5];
  const float* encW2 = (const float*)d_in[6];
  const float* encb2 = (const float*)d_in[7];
  const float* edgW1 = (const float*)d_in[12];
  const float* edgb1 = (const float*)d_in[13];
  const float* edgW2 = (const float*)d_in[14];
  const float* edgb2 = (const float*)d_in[15];
  const float* Wih   = (const float*)d_in[16];
  const float* Whh   = (const float*)d_in[17];
  const float* bih   = (const float*)d_in[18];
  const float* bhh   = (const float*)d_in[19];
  const float* mW1   = (const float*)d_in[20];
  const float* mb1   = (const float*)d_in[21];
  const float* mW2   = (const float*)d_in[22];
  const float* mb2   = (const float*)d_in[23];
  const float* tW1   = (const float*)d_in[24];
  const float* tb1   = (const float*)d_in[25];
  const float* tW2   = (const float*)d_in[26];
  const float* tb2   = (const float*)d_in[27];

  float* out = (float*)d_out;
  float* ws  = (float*)d_ws;
  float* ctx  = ws;                       // 512*320
  float* P    = ws + 163840;
  float* Q    = ws + 327680;
  float* agg  = ws + 491520;
  float* hbuf = ws + 655360;
  unsigned short* ub = (unsigned short*)(ws + 819200);
  unsigned short* W2bf  = ub;             // 102400 u
  unsigned short* WihBf = ub + 102400;    // 614400 u
  unsigned short* WhhBf = ub + 716800;    // 307200 u
  unsigned short* T1bf  = ub + 1024000;   // 614400 u
  unsigned short* T2bf  = ub + 1638400;   // 307200 u

  k_cvt<<<950, 256, 0, stream>>>(edgW2, Wih, Whh, tW1, tW2, ub);
  k_encoder<<<128, 256, 0, stream>>>(feat, attr, encW1, encb1, encW2, encb2, ctx);
  k_pq<<<128, 320, 0, stream>>>(ctx, edgW1, edgb1, P, Q);
  k_edge<<<512, 256, 0, stream>>>(P, Q, pos, edgW1, W2bf, edgb2, agg);
  k_gruM<<<80, 256, 0, stream>>>(ctx, agg, WihBf, WhhBf, bih, bhh, hbuf);
  k_mode<<<512, 320, 0, stream>>>(hbuf, mW1, mb1, mW2, mb2, out);
  k_trajM<<<dim3(16, 6), 256, 0, stream>>>(hbuf, T1bf, tb1, T2bf, tb2, out);
}

// Round 4
// 121.101 us; speedup vs baseline: 3.5930x; 1.7202x over previous
//
#include <hip/hip_runtime.h>

// ---------------------------------------------------------------------------
// Sizes: B=8, N=64, FD=128, HD=256, MD=64, D=320, NM=6, FS=80, rows=B*N=512
// ---------------------------------------------------------------------------

typedef __attribute__((ext_vector_type(8))) short bf16x8;   // 8 bf16 (4 VGPR)
typedef __attribute__((ext_vector_type(4))) float f32x4;

__device__ __forceinline__ unsigned short f2bf(float x) {   // RNE f32->bf16
  unsigned u = __float_as_uint(x);
  return (unsigned short)((u + 0x7fffu + ((u >> 16) & 1u)) >> 16);
}

// ---- JAX threefry2x32 (20 rounds), key = [0, 42] ---------------------------
__device__ __forceinline__ void threefry2x32(unsigned k0, unsigned k1,
                                             unsigned& x0, unsigned& x1) {
  const unsigned ks0 = k0, ks1 = k1, ks2 = k0 ^ k1 ^ 0x1BD11BDAu;
  x0 += ks0; x1 += ks1;
#define TFR(r) { x0 += x1; x1 = (x1 << (r)) | (x1 >> (32 - (r))); x1 ^= x0; }
  TFR(13) TFR(15) TFR(26) TFR(6)  x0 += ks1; x1 += ks2 + 1u;
  TFR(17) TFR(29) TFR(16) TFR(24) x0 += ks2; x1 += ks0 + 2u;
  TFR(13) TFR(15) TFR(26) TFR(6)  x0 += ks0; x1 += ks1 + 3u;
  TFR(17) TFR(29) TFR(16) TFR(24) x0 += ks1; x1 += ks2 + 4u;
  TFR(13) TFR(15) TFR(26) TFR(6)  x0 += ks2; x1 += ks0 + 5u;
#undef TFR
}

__device__ __forceinline__ float erfinv_xla(float x) {
  float w = -logf((1.0f - x) * (1.0f + x));
  float p;
  if (w < 5.0f) {
    w = w - 2.5f;
    p = 2.81022636e-08f;
    p = fmaf(p, w, 3.43273939e-07f);
    p = fmaf(p, w, -3.5233877e-06f);
    p = fmaf(p, w, -4.39150654e-06f);
    p = fmaf(p, w, 0.00021858087f);
    p = fmaf(p, w, -0.00125372503f);
    p = fmaf(p, w, -0.00417768164f);
    p = fmaf(p, w, 0.246640727f);
    p = fmaf(p, w, 1.50140941f);
  } else {
    w = sqrtf(w) - 3.0f;
    p = -0.000200214257f;
    p = fmaf(p, w, 0.000100950558f);
    p = fmaf(p, w, 0.00134934322f);
    p = fmaf(p, w, -0.00367342844f);
    p = fmaf(p, w, 0.00573950773f);
    p = fmaf(p, w, -0.0076224613f);
    p = fmaf(p, w, 0.00943887047f);
    p = fmaf(p, w, 1.00167406f);
    p = fmaf(p, w, 2.83297682f);
  }
  return p * x;
}

__device__ __forceinline__ float jax_normal42(unsigned idx) {
  unsigned x0 = 0u, x1 = idx;
  threefry2x32(0u, 42u, x0, x1);
  unsigned bits = x0 ^ x1;
  float f = __uint_as_float((bits >> 9) | 0x3f800000u) - 1.0f;
  const float lo = -0.99999994f;
  float u = fmaxf(lo, f * 2.0f + lo);
  return 1.41421356237f * erfinv_xla(u);
}

// ---------------------------------------------------------------------------
// K0: fused weight converter f32 -> bf16 fragment layout [k>>3][n][k&7].
// ---------------------------------------------------------------------------
__global__ __launch_bounds__(256)
void k_cvt(const float* __restrict__ W2e, const float* __restrict__ Wih,
           const float* __restrict__ Whh, const float* __restrict__ T1,
           const float* __restrict__ T2, unsigned short* __restrict__ ub) {
  const int id = blockIdx.x * 256 + threadIdx.x;
  const float* src;
  unsigned short* dst;
  int rem, N;
  if (id < 12800)       { src = W2e; dst = ub;           rem = id;          N = 320; }
  else if (id < 89600)  { src = Wih; dst = ub + 102400;  rem = id - 12800;  N = 960; }
  else if (id < 128000) { src = Whh; dst = ub + 716800;  rem = id - 89600;  N = 960; }
  else if (id < 204800) { src = T1;  dst = ub + 1024000; rem = id - 128000; N = 320; }
  else                  { src = T2;  dst = ub + 1638400; rem = id - 204800; N = 160; }
  const int g = rem / N, n = rem - g * N;
  const float* s = src + g * 8 * N + n;
  unsigned short v[8];
#pragma unroll
  for (int e = 0; e < 8; ++e) v[e] = f2bf(s[e * N]);
  ushort4* d = (ushort4*)&dst[(size_t)rem * 8];
  d[0] = make_ushort4(v[0], v[1], v[2], v[3]);
  d[1] = make_ushort4(v[4], v[5], v[6], v[7]);
}

// ---------------------------------------------------------------------------
// K1: object encoder -> ctx[:,0:256]=emb ; ctx[:,256:320]=sampled
// ---------------------------------------------------------------------------
__global__ __launch_bounds__(256)
void k_encoder(const float* __restrict__ feat, const float* __restrict__ attr,
               const float* __restrict__ W1, const float* __restrict__ b1,
               const float* __restrict__ W2, const float* __restrict__ b2,
               float* __restrict__ ctx) {
  __shared__ float s_in[4][136];
  __shared__ float s_h1[4][256];
  const int r0 = blockIdx.x * 4;
  const int t = threadIdx.x;
  for (int r = 0; r < 4; ++r) {
    if (t < 128)      s_in[r][t] = feat[(r0 + r) * 128 + t];
    else if (t < 136) s_in[r][t] = attr[(r0 + r) * 8 + (t - 128)];
  }
  __syncthreads();
  float acc[4];
#pragma unroll
  for (int r = 0; r < 4; ++r) acc[r] = b1[t];
  for (int k = 0; k < 136; ++k) {
    const float w = W1[k * 256 + t];
#pragma unroll
    for (int r = 0; r < 4; ++r) acc[r] = fmaf(s_in[r][k], w, acc[r]);
  }
#pragma unroll
  for (int r = 0; r < 4; ++r) s_h1[r][t] = fmaxf(acc[r], 0.0f);
  __syncthreads();
#pragma unroll
  for (int r = 0; r < 4; ++r) acc[r] = b2[t];
  for (int k = 0; k < 256; ++k) {
    const float w = W2[k * 256 + t];
#pragma unroll
    for (int r = 0; r < 4; ++r) acc[r] = fmaf(s_h1[r][k], w, acc[r]);
  }
#pragma unroll
  for (int r = 0; r < 4; ++r) ctx[(r0 + r) * 320 + t] = fmaxf(acc[r], 0.0f);
  if (t < 64) {
    for (int r = 0; r < 4; ++r)
      ctx[(r0 + r) * 320 + 256 + t] = jax_normal42((unsigned)((r0 + r) * 64 + t));
  }
}

// ---------------------------------------------------------------------------
// K2: P = ctx @ W1[0:320] + b1 ; Q = ctx @ W1[320:640]
// ---------------------------------------------------------------------------
__global__ __launch_bounds__(320)
void k_pq(const float* __restrict__ ctx, const float* __restrict__ W1,
          const float* __restrict__ b1, float* __restrict__ P,
          float* __restrict__ Q) {
  __shared__ float s_c[4][320];
  const int r0 = blockIdx.x * 4;
  const int t = threadIdx.x;
#pragma unroll
  for (int r = 0; r < 4; ++r) s_c[r][t] = ctx[(r0 + r) * 320 + t];
  __syncthreads();
  float p[4], q[4];
#pragma unroll
  for (int r = 0; r < 4; ++r) { p[r] = b1[t]; q[r] = 0.0f; }
  for (int k = 0; k < 320; ++k) {
    const float wp = W1[k * 320 + t];
    const float wq = W1[(320 + k) * 320 + t];
#pragma unroll
    for (int r = 0; r < 4; ++r) {
      const float c = s_c[r][k];
      p[r] = fmaf(c, wp, p[r]);
      q[r] = fmaf(c, wq, q[r]);
    }
  }
#pragma unroll
  for (int r = 0; r < 4; ++r) {
    P[(r0 + r) * 320 + t] = p[r];
    Q[(r0 + r) * 320 + t] = q[r];
  }
}

// ---------------------------------------------------------------------------
// K3: edge MLP (layer1 rank-reduced + layer2 via MFMA) + masked mean, fused.
// grid 512 (one block per (b,i)), block 256 = 4 waves.
// ---------------------------------------------------------------------------
__global__ __launch_bounds__(256)
void k_edge(const float* __restrict__ P, const float* __restrict__ Q,
            const float* __restrict__ pos, const float* __restrict__ W1,
            const unsigned short* __restrict__ Bf, const float* __restrict__ b2,
            float* __restrict__ agg) {
  __shared__ __align__(16) unsigned short s_A[40 * 64 * 8];  // 40 KB
  const int bx = blockIdx.x;
  const int b = bx >> 6, i = bx & 63;
  const int t = threadIdx.x;
  const int w = t >> 6, l = t & 63;

  {
    const int j = t & 63;
    const int sub = t >> 6;
    const float2 pi = *(const float2*)&pos[b * 128 + 2 * i];
    const float2 pj = *(const float2*)&pos[b * 128 + 2 * j];
    const float rx = pi.x - pj.x, ry = pi.y - pj.y;
    const float* __restrict__ Prow = P + bx * 320;
    const float* __restrict__ Qrow = Q + (b * 64 + j) * 320;
    const float* __restrict__ w0 = W1 + 640 * 320;
    const float* __restrict__ w1 = W1 + 641 * 320;
#pragma unroll
    for (int g = 0; g < 10; ++g) {
      const int k0 = g * 32 + sub * 8;
      const float4 p0 = *(const float4*)&Prow[k0];
      const float4 p1 = *(const float4*)&Prow[k0 + 4];
      const float4 q0 = *(const float4*)&Qrow[k0];
      const float4 q1 = *(const float4*)&Qrow[k0 + 4];
      const float4 a0 = *(const float4*)&w0[k0];
      const float4 a1 = *(const float4*)&w0[k0 + 4];
      const float4 c0 = *(const float4*)&w1[k0];
      const float4 c1 = *(const float4*)&w1[k0 + 4];
      float v[8];
      v[0] = fmaf(ry, c0.x, fmaf(rx, a0.x, p0.x + q0.x));
      v[1] = fmaf(ry, c0.y, fmaf(rx, a0.y, p0.y + q0.y));
      v[2] = fmaf(ry, c0.z, fmaf(rx, a0.z, p0.z + q0.z));
      v[3] = fmaf(ry, c0.w, fmaf(rx, a0.w, p0.w + q0.w));
      v[4] = fmaf(ry, c1.x, fmaf(rx, a1.x, p1.x + q1.x));
      v[5] = fmaf(ry, c1.y, fmaf(rx, a1.y, p1.y + q1.y));
      v[6] = fmaf(ry, c1.z, fmaf(rx, a1.z, p1.z + q1.z));
      v[7] = fmaf(ry, c1.w, fmaf(rx, a1.w, p1.w + q1.w));
      unsigned short u[8];
#pragma unroll
      for (int e = 0; e < 8; ++e) u[e] = f2bf(fmaxf(v[e], 0.0f));
      ushort4* dst = (ushort4*)&s_A[((g * 4 + sub) * 64 + j) * 8];
      dst[0] = make_ushort4(u[0], u[1], u[2], u[3]);
      dst[1] = make_ushort4(u[4], u[5], u[6], u[7]);
    }
  }
  __syncthreads();

  f32x4 acc[4][5];
#pragma unroll
  for (int mt = 0; mt < 4; ++mt)
#pragma unroll
    for (int u = 0; u < 5; ++u) acc[mt][u] = (f32x4){0.f, 0.f, 0.f, 0.f};

  const int lg = l >> 4, lr = l & 15;
  const unsigned short* __restrict__ Bbase = Bf + (lg * 320 + w * 80 + lr) * 8;
  const unsigned short* __restrict__ Abase = s_A + lg * 512 + lr * 8;

#pragma unroll 2
  for (int ks = 0; ks < 10; ++ks) {
    bf16x8 afr[4];
#pragma unroll
    for (int mt = 0; mt < 4; ++mt)
      afr[mt] = *(const bf16x8*)(Abase + ks * 2048 + mt * 128);
    bf16x8 bfr[5];
#pragma unroll
    for (int u = 0; u < 5; ++u)
      bfr[u] = *(const bf16x8*)(Bbase + ks * 10240 + u * 128);
#pragma unroll
    for (int mt = 0; mt < 4; ++mt)
#pragma unroll
      for (int u = 0; u < 5; ++u)
        acc[mt][u] = __builtin_amdgcn_mfma_f32_16x16x32_bf16(
            afr[mt], bfr[u], acc[mt][u], 0, 0, 0);
  }

#pragma unroll
  for (int u = 0; u < 5; ++u) {
    const int n = w * 80 + u * 16 + lr;
    const float bias = b2[n];
    float p = 0.0f;
#pragma unroll
    for (int mt = 0; mt < 4; ++mt) {
#pragma unroll
      for (int r = 0; r < 4; ++r) {
        const int j = mt * 16 + lg * 4 + r;
        const float e = fmaxf(acc[mt][u][r] + bias, 0.0f);
        p += (j != i) ? e : 0.0f;
      }
    }
    p += __shfl_xor(p, 16);
    p += __shfl_xor(p, 32);
    if (l < 16) agg[bx * 320 + n] = p * (1.0f / 63.0f);
  }
}

// ---------------------------------------------------------------------------
// K4: GRUCell via MFMA, fused pointwise.
// grid 80 = (row-block 16) x (d-block 5); block 256 = 4 waves.
// ---------------------------------------------------------------------------
__global__ __launch_bounds__(256)
void k_gruM(const float* __restrict__ ctx, const float* __restrict__ agg,
            const unsigned short* __restrict__ BfI,
            const unsigned short* __restrict__ BfH,
            const float* __restrict__ bih, const float* __restrict__ bhh,
            float* __restrict__ h) {
  __shared__ __align__(16) unsigned short s_x[80 * 32 * 8];  // 40 KB
  const int rb = blockIdx.x / 5, db = blockIdx.x % 5;
  const int row0 = rb * 32, d0 = db * 64;
  const int t = threadIdx.x;

  {
    const int r = t >> 3, ob = t & 7;
    const int row = row0 + r;
#pragma unroll
    for (int it = 0; it < 10; ++it) {
      const int oct = ob + it * 8;  // 0..79
      float4 v0, v1;
      if (oct < 40) {
        v0 = *(const float4*)&ctx[row * 320 + oct * 8];
        v1 = *(const float4*)&ctx[row * 320 + oct * 8 + 4];
      } else {
        v0 = *(const float4*)&agg[row * 320 + (oct - 40) * 8];
        v1 = *(const float4*)&agg[row * 320 + (oct - 40) * 8 + 4];
      }
      ushort4* dst = (ushort4*)&s_x[(oct * 32 + r) * 8];
      dst[0] = make_ushort4(f2bf(v0.x), f2bf(v0.y), f2bf(v0.z), f2bf(v0.w));
      dst[1] = make_ushort4(f2bf(v1.x), f2bf(v1.y), f2bf(v1.z), f2bf(v1.w));
    }
  }
  __syncthreads();

  const int w = t >> 6, l = t & 63, lg = l >> 4, lr = l & 15;
  const int d = d0 + w * 16 + lr;

  f32x4 accI[2][3], accH[2][3];
#pragma unroll
  for (int mt = 0; mt < 2; ++mt)
#pragma unroll
    for (int g = 0; g < 3; ++g) {
      accI[mt][g] = (f32x4){0.f, 0.f, 0.f, 0.f};
      accH[mt][g] = (f32x4){0.f, 0.f, 0.f, 0.f};
    }

#pragma unroll 2
  for (int ks = 0; ks < 20; ++ks) {
    bf16x8 afr[2];
#pragma unroll
    for (int mt = 0; mt < 2; ++mt)
      afr[mt] = *(const bf16x8*)&s_x[(((ks * 4 + lg) * 32) + mt * 16 + lr) * 8];
    bf16x8 bfr[3];
#pragma unroll
    for (int g = 0; g < 3; ++g)
      bfr[g] = *(const bf16x8*)&BfI[((ks * 4 + lg) * 960 + g * 320 + d) * 8];
#pragma unroll
    for (int mt = 0; mt < 2; ++mt)
#pragma unroll
      for (int g = 0; g < 3; ++g)
        accI[mt][g] = __builtin_amdgcn_mfma_f32_16x16x32_bf16(
            afr[mt], bfr[g], accI[mt][g], 0, 0, 0);
  }
#pragma unroll 2
  for (int ks = 0; ks < 10; ++ks) {
    bf16x8 afr[2];
#pragma unroll
    for (int mt = 0; mt < 2; ++mt)
      afr[mt] = *(const bf16x8*)&s_x[(((ks * 4 + lg) * 32) + mt * 16 + lr) * 8];
    bf16x8 bfr[3];
#pragma unroll
    for (int g = 0; g < 3; ++g)
      bfr[g] = *(const bf16x8*)&BfH[((ks * 4 + lg) * 960 + g * 320 + d) * 8];
#pragma unroll
    for (int mt = 0; mt < 2; ++mt)
#pragma unroll
      for (int g = 0; g < 3; ++g)
        accH[mt][g] = __builtin_amdgcn_mfma_f32_16x16x32_bf16(
            afr[mt], bfr[g], accH[mt][g], 0, 0, 0);
  }

  const float b_ir = bih[d], b_iz = bih[320 + d], b_in = bih[640 + d];
  const float b_hr = bhh[d], b_hz = bhh[320 + d], b_hn = bhh[640 + d];
#pragma unroll
  for (int mt = 0; mt < 2; ++mt) {
#pragma unroll
    for (int r = 0; r < 4; ++r) {
      const int row = row0 + mt * 16 + lg * 4 + r;
      const float ir = accI[mt][0][r] + b_ir;
      const float iz = accI[mt][1][r] + b_iz;
      const float inn = accI[mt][2][r] + b_in;
      const float hr = accH[mt][0][r] + b_hr;
      const float hz = accH[mt][1][r] + b_hz;
      const float hn = accH[mt][2][r] + b_hn;
      const float rr = 1.0f / (1.0f + expf(-(ir + hr)));
      const float zz = 1.0f / (1.0f + expf(-(iz + hz)));
      const float nn = tanhf(fmaf(rr, hn, inn));
      const float c = ctx[row * 320 + d];
      h[row * 320 + d] = (1.0f - zz) * nn + zz * c;
    }
  }
}

// ---------------------------------------------------------------------------
// K5a: mode head + softmax.  grid 512, block 320
// ---------------------------------------------------------------------------
__global__ __launch_bounds__(320)
void k_mode(const float* __restrict__ h, const float* __restrict__ W1,
            const float* __restrict__ b1, const float* __restrict__ W2,
            const float* __restrict__ b2, float* __restrict__ out) {
  __shared__ float s_h[320];
  __shared__ float s_m[320];
  __shared__ float s_l[6];
  const int row = blockIdx.x;
  const int t = threadIdx.x;
  s_h[t] = h[row * 320 + t];
  __syncthreads();
  float a = b1[t];
  for (int k = 0; k < 320; ++k) a = fmaf(s_h[k], W1[k * 320 + t], a);
  s_m[t] = fmaxf(a, 0.0f);
  __syncthreads();
  if (t < 6) {
    float l = b2[t];
    for (int k = 0; k < 320; ++k) l = fmaf(s_m[k], W2[k * 6 + t], l);
    s_l[t] = l;
  }
  __syncthreads();
  if (t < 6) {
    float mx = s_l[0];
#pragma unroll
    for (int q = 1; q < 6; ++q) mx = fmaxf(mx, s_l[q]);
    float sum = 0.0f;
#pragma unroll
    for (int q = 0; q < 6; ++q) sum += expf(s_l[q] - mx);
    out[491520 + row * 6 + t] = expf(s_l[t] - mx) / sum;
  }
}

// ---------------------------------------------------------------------------
// K5b: trajectory head via MFMA, both GEMMs fused. ALL loop bounds
// compile-time (rule #20: runtime-indexed frag/acc arrays -> scratch).
// grid (32, 6); block 256 = 4 waves. Block: rows [rb*16,+16), mode m.
// GEMM2: wave w covers n-tiles {nb..nb+2}, nb={0,3,6,7} (7,8 dup = benign).
// ---------------------------------------------------------------------------
__global__ __launch_bounds__(256)
void k_trajM(const float* __restrict__ h, const unsigned short* __restrict__ B1,
             const float* __restrict__ b1, const unsigned short* __restrict__ B2,
             const float* __restrict__ b2, float* __restrict__ out) {
  __shared__ __align__(16) unsigned short s_h[40 * 16 * 8];  // 10 KB
  __shared__ __align__(16) unsigned short s_t[40 * 16 * 8];  // 10 KB
  const int rb = blockIdx.x, m = blockIdx.y;
  const int row0 = rb * 16;
  const int t = threadIdx.x;

  // stage h rows -> bf16 fragment layout [oct][row][8]
#pragma unroll
  for (int it = 0; it < 3; ++it) {
    const int idx = t + it * 256;
    if (idx < 640) {
      const int row = idx / 40, oct = idx - row * 40;
      const float4 v0 = *(const float4*)&h[(row0 + row) * 320 + oct * 8];
      const float4 v1 = *(const float4*)&h[(row0 + row) * 320 + oct * 8 + 4];
      ushort4* dst = (ushort4*)&s_h[(oct * 16 + row) * 8];
      dst[0] = make_ushort4(f2bf(v0.x), f2bf(v0.y), f2bf(v0.z), f2bf(v0.w));
      dst[1] = make_ushort4(f2bf(v1.x), f2bf(v1.y), f2bf(v1.z), f2bf(v1.w));
    }
  }
  __syncthreads();

  const int w = t >> 6, l = t & 63, lg = l >> 4, lr = l & 15;

  // GEMM1: N=320, wave w -> n = w*80 + u*16 + lr; M=16 (single m-tile)
  f32x4 acc1[5];
#pragma unroll
  for (int u = 0; u < 5; ++u) acc1[u] = (f32x4){0.f, 0.f, 0.f, 0.f};
  const unsigned short* __restrict__ B1m = B1 + m * 102400;
#pragma unroll
  for (int ks = 0; ks < 10; ++ks) {
    const bf16x8 afr = *(const bf16x8*)&s_h[((ks * 4 + lg) * 16 + lr) * 8];
    bf16x8 bfr[5];
#pragma unroll
    for (int u = 0; u < 5; ++u)
      bfr[u] = *(const bf16x8*)&B1m[((ks * 4 + lg) * 320 + w * 80 + u * 16 + lr) * 8];
#pragma unroll
    for (int u = 0; u < 5; ++u)
      acc1[u] = __builtin_amdgcn_mfma_f32_16x16x32_bf16(afr, bfr[u], acc1[u], 0, 0, 0);
  }
  // epilogue1: relu(+b1) -> s_t (fragment layout)
#pragma unroll
  for (int u = 0; u < 5; ++u) {
    const int n = w * 80 + u * 16 + lr;
    const float bias = b1[m * 320 + n];
#pragma unroll
    for (int r = 0; r < 4; ++r) {
      const int row = lg * 4 + r;
      s_t[((n >> 3) * 16 + row) * 8 + (n & 7)] =
          f2bf(fmaxf(acc1[u][r] + bias, 0.0f));
    }
  }
  __syncthreads();

  // GEMM2: N=160; wave w -> n-tiles nb..nb+2, nb={0,3,6,7}
  const int nb = (w == 0) ? 0 : (w == 1) ? 3 : (w == 2) ? 6 : 7;
  f32x4 acc2[3];
#pragma unroll
  for (int u = 0; u < 3; ++u) acc2[u] = (f32x4){0.f, 0.f, 0.f, 0.f};
  const unsigned short* __restrict__ B2m = B2 + m * 51200;
#pragma unroll
  for (int ks = 0; ks < 10; ++ks) {
    const bf16x8 afr = *(const bf16x8*)&s_t[((ks * 4 + lg) * 16 + lr) * 8];
    bf16x8 bfr[3];
#pragma unroll
    for (int u = 0; u < 3; ++u)
      bfr[u] = *(const bf16x8*)&B2m[((ks * 4 + lg) * 160 + (nb + u) * 16 + lr) * 8];
#pragma unroll
    for (int u = 0; u < 3; ++u)
      acc2[u] = __builtin_amdgcn_mfma_f32_16x16x32_bf16(afr, bfr[u], acc2[u], 0, 0, 0);
  }
#pragma unroll
  for (int u = 0; u < 3; ++u) {
    const int n = (nb + u) * 16 + lr;
    const float bias = b2[m * 160 + n];
#pragma unroll
    for (int r = 0; r < 4; ++r) {
      const int row = row0 + lg * 4 + r;
      out[(row * 6 + m) * 160 + n] = acc2[u][r] + bias;
    }
  }
}

// ---------------------------------------------------------------------------
extern "C" void kernel_launch(void* const* d_in, const int* in_sizes, int n_in,
                              void* d_out, int out_size, void* d_ws, size_t ws_size,
                              hipStream_t stream) {
  (void)in_sizes; (void)n_in; (void)out_size; (void)ws_size;
  const float* feat  = (const float*)d_in[0];
  const float* attr  = (const float*)d_in[1];
  const float* pos   = (const float*)d_in[3];
  const float* encW1 = (const float*)d_in[4];
  const float* encb1 = (const float*)d_in[5];
  const float* encW2 = (const float*)d_in[6];
  const float* encb2 = (const float*)d_in[7];
  const float* edgW1 = (const float*)d_in[12];
  const float* edgb1 = (const float*)d_in[13];
  const float* edgW2 = (const float*)d_in[14];
  const float* edgb2 = (const float*)d_in[15];
  const float* Wih   = (const float*)d_in[16];
  const float* Whh   = (const float*)d_in[17];
  const float* bih   = (const float*)d_in[18];
  const float* bhh   = (const float*)d_in[19];
  const float* mW1   = (const float*)d_in[20];
  const float* mb1   = (const float*)d_in[21];
  const float* mW2   = (const float*)d_in[22];
  const float* mb2   = (const float*)d_in[23];
  const float* tW1   = (const float*)d_in[24];
  const float* tb1   = (const float*)d_in[25];
  const float* tW2   = (const float*)d_in[26];
  const float* tb2   = (const float*)d_in[27];

  float* out = (float*)d_out;
  float* ws  = (float*)d_ws;
  float* ctx  = ws;                       // 512*320
  float* P    = ws + 163840;
  float* Q    = ws + 327680;
  float* agg  = ws + 491520;
  float* hbuf = ws + 655360;
  unsigned short* ub = (unsigned short*)(ws + 819200);
  unsigned short* W2bf  = ub;             // 102400 u
  unsigned short* WihBf = ub + 102400;    // 614400 u
  unsigned short* WhhBf = ub + 716800;    // 307200 u
  unsigned short* T1bf  = ub + 1024000;   // 614400 u
  unsigned short* T2bf  = ub + 1638400;   // 307200 u

  k_cvt<<<950, 256, 0, stream>>>(edgW2, Wih, Whh, tW1, tW2, ub);
  k_encoder<<<128, 256, 0, stream>>>(feat, attr, encW1, encb1, encW2, encb2, ctx);
  k_pq<<<128, 320, 0, stream>>>(ctx, edgW1, edgb1, P, Q);
  k_edge<<<512, 256, 0, stream>>>(P, Q, pos, edgW1, W2bf, edgb2, agg);
  k_gruM<<<80, 256, 0, stream>>>(ctx, agg, WihBf, WhhBf, bih, bhh, hbuf);
  k_mode<<<512, 320, 0, stream>>>(hbuf, mW1, mb1, mW2, mb2, out);
  k_trajM<<<dim3(32, 6), 256, 0, stream>>>(hbuf, T1bf, tb1, T2bf, tb2, out);
}

// Round 5
// 87.478 us; speedup vs baseline: 4.9740x; 1.3844x over previous
//
#include <hip/hip_runtime.h>

// ---------------------------------------------------------------------------
// Sizes: B=8, N=64, FD=128, HD=256, MD=64, D=320, NM=6, FS=80, rows=B*N=512
// ---------------------------------------------------------------------------

typedef __attribute__((ext_vector_type(8))) short bf16x8;   // 8 bf16 (4 VGPR)
typedef __attribute__((ext_vector_type(4))) float f32x4;

__device__ __forceinline__ unsigned short f2bf(float x) {   // RNE f32->bf16
  unsigned u = __float_as_uint(x);
  return (unsigned short)((u + 0x7fffu + ((u >> 16) & 1u)) >> 16);
}

// ---- JAX threefry2x32 (20 rounds), key = [0, 42] ---------------------------
__device__ __forceinline__ void threefry2x32(unsigned k0, unsigned k1,
                                             unsigned& x0, unsigned& x1) {
  const unsigned ks0 = k0, ks1 = k1, ks2 = k0 ^ k1 ^ 0x1BD11BDAu;
  x0 += ks0; x1 += ks1;
#define TFR(r) { x0 += x1; x1 = (x1 << (r)) | (x1 >> (32 - (r))); x1 ^= x0; }
  TFR(13) TFR(15) TFR(26) TFR(6)  x0 += ks1; x1 += ks2 + 1u;
  TFR(17) TFR(29) TFR(16) TFR(24) x0 += ks2; x1 += ks0 + 2u;
  TFR(13) TFR(15) TFR(26) TFR(6)  x0 += ks0; x1 += ks1 + 3u;
  TFR(17) TFR(29) TFR(16) TFR(24) x0 += ks1; x1 += ks2 + 4u;
  TFR(13) TFR(15) TFR(26) TFR(6)  x0 += ks2; x1 += ks0 + 5u;
#undef TFR
}

__device__ __forceinline__ float erfinv_xla(float x) {
  float w = -logf((1.0f - x) * (1.0f + x));
  float p;
  if (w < 5.0f) {
    w = w - 2.5f;
    p = 2.81022636e-08f;
    p = fmaf(p, w, 3.43273939e-07f);
    p = fmaf(p, w, -3.5233877e-06f);
    p = fmaf(p, w, -4.39150654e-06f);
    p = fmaf(p, w, 0.00021858087f);
    p = fmaf(p, w, -0.00125372503f);
    p = fmaf(p, w, -0.00417768164f);
    p = fmaf(p, w, 0.246640727f);
    p = fmaf(p, w, 1.50140941f);
  } else {
    w = sqrtf(w) - 3.0f;
    p = -0.000200214257f;
    p = fmaf(p, w, 0.000100950558f);
    p = fmaf(p, w, 0.00134934322f);
    p = fmaf(p, w, -0.00367342844f);
    p = fmaf(p, w, 0.00573950773f);
    p = fmaf(p, w, -0.0076224613f);
    p = fmaf(p, w, 0.00943887047f);
    p = fmaf(p, w, 1.00167406f);
    p = fmaf(p, w, 2.83297682f);
  }
  return p * x;
}

__device__ __forceinline__ float jax_normal42(unsigned idx) {
  unsigned x0 = 0u, x1 = idx;
  threefry2x32(0u, 42u, x0, x1);
  unsigned bits = x0 ^ x1;
  float f = __uint_as_float((bits >> 9) | 0x3f800000u) - 1.0f;
  const float lo = -0.99999994f;
  float u = fmaxf(lo, f * 2.0f + lo);
  return 1.41421356237f * erfinv_xla(u);
}

// ---------------------------------------------------------------------------
// K0: fused weight converter f32 -> bf16 fragment layout [k>>3][n][k&7].
// jobs (octets): W2e 12800 | Wih 76800 | Whh 38400 | T1 76800 | T2 38400 |
//                EW1 25600 | MW1 12800 | MW2pad 640   => 282240, grid 1103
// ---------------------------------------------------------------------------
__global__ __launch_bounds__(256)
void k_cvt(const float* __restrict__ W2e, const float* __restrict__ Wih,
           const float* __restrict__ Whh, const float* __restrict__ T1,
           const float* __restrict__ T2, const float* __restrict__ EW1,
           const float* __restrict__ MW1, const float* __restrict__ MW2,
           unsigned short* __restrict__ ub) {
  const int id = blockIdx.x * 256 + threadIdx.x;
  if (id >= 282240) return;
  if (id >= 281600) {  // MW2 padded to 16 cols
    const int rem = id - 281600;
    const int g = rem >> 4, n = rem & 15;
    unsigned short v[8];
#pragma unroll
    for (int e = 0; e < 8; ++e) v[e] = (n < 6) ? f2bf(MW2[(g * 8 + e) * 6 + n]) : 0;
    ushort4* d = (ushort4*)&ub[2252800 + (size_t)rem * 8];
    d[0] = make_ushort4(v[0], v[1], v[2], v[3]);
    d[1] = make_ushort4(v[4], v[5], v[6], v[7]);
    return;
  }
  const float* src;
  unsigned short* dst;
  int rem, N;
  if (id < 12800)       { src = W2e; dst = ub;           rem = id;          N = 320; }
  else if (id < 89600)  { src = Wih; dst = ub + 102400;  rem = id - 12800;  N = 960; }
  else if (id < 128000) { src = Whh; dst = ub + 716800;  rem = id - 89600;  N = 960; }
  else if (id < 204800) { src = T1;  dst = ub + 1024000; rem = id - 128000; N = 320; }
  else if (id < 243200) { src = T2;  dst = ub + 1638400; rem = id - 204800; N = 160; }
  else if (id < 268800) { src = EW1; dst = ub + 1945600; rem = id - 243200; N = 320; }
  else                  { src = MW1; dst = ub + 2150400; rem = id - 268800; N = 320; }
  const int g = rem / N, n = rem - g * N;
  const float* s = src + g * 8 * N + n;
  unsigned short v[8];
#pragma unroll
  for (int e = 0; e < 8; ++e) v[e] = f2bf(s[e * N]);
  ushort4* d = (ushort4*)&dst[(size_t)rem * 8];
  d[0] = make_ushort4(v[0], v[1], v[2], v[3]);
  d[1] = make_ushort4(v[4], v[5], v[6], v[7]);
}

// ---------------------------------------------------------------------------
// K1: object encoder -> ctx[:,0:256]=emb ; ctx[:,256:320]=sampled
// ---------------------------------------------------------------------------
__global__ __launch_bounds__(256)
void k_encoder(const float* __restrict__ feat, const float* __restrict__ attr,
               const float* __restrict__ W1, const float* __restrict__ b1,
               const float* __restrict__ W2, const float* __restrict__ b2,
               float* __restrict__ ctx) {
  __shared__ float s_in[4][136];
  __shared__ float s_h1[4][256];
  const int r0 = blockIdx.x * 4;
  const int t = threadIdx.x;
  for (int r = 0; r < 4; ++r) {
    if (t < 128)      s_in[r][t] = feat[(r0 + r) * 128 + t];
    else if (t < 136) s_in[r][t] = attr[(r0 + r) * 8 + (t - 128)];
  }
  __syncthreads();
  float acc[4];
#pragma unroll
  for (int r = 0; r < 4; ++r) acc[r] = b1[t];
  for (int k = 0; k < 136; ++k) {
    const float w = W1[k * 256 + t];
#pragma unroll
    for (int r = 0; r < 4; ++r) acc[r] = fmaf(s_in[r][k], w, acc[r]);
  }
#pragma unroll
  for (int r = 0; r < 4; ++r) s_h1[r][t] = fmaxf(acc[r], 0.0f);
  __syncthreads();
#pragma unroll
  for (int r = 0; r < 4; ++r) acc[r] = b2[t];
  for (int k = 0; k < 256; ++k) {
    const float w = W2[k * 256 + t];
#pragma unroll
    for (int r = 0; r < 4; ++r) acc[r] = fmaf(s_h1[r][k], w, acc[r]);
  }
#pragma unroll
  for (int r = 0; r < 4; ++r) ctx[(r0 + r) * 320 + t] = fmaxf(acc[r], 0.0f);
  if (t < 64) {
    for (int r = 0; r < 4; ++r)
      ctx[(r0 + r) * 320 + 256 + t] = jax_normal42((unsigned)((r0 + r) * 64 + t));
  }
}

// ---------------------------------------------------------------------------
// K2: P/Q via MFMA.  grid (32 rb, 2 half), block 256 = 4 waves.
// rows [rb*16,+16); half 0 -> P (+b1), half 1 -> Q.  B = EW1bf (K=640 frags).
// ---------------------------------------------------------------------------
__global__ __launch_bounds__(256)
void k_pqM(const float* __restrict__ ctx, const unsigned short* __restrict__ Bf,
           const float* __restrict__ b1, float* __restrict__ P,
           float* __restrict__ Q) {
  __shared__ __align__(16) unsigned short s_c[40 * 16 * 8];  // 10 KB
  const int row0 = blockIdx.x * 16;
  const int half = blockIdx.y;
  const int t = threadIdx.x;
#pragma unroll
  for (int it = 0; it < 3; ++it) {
    const int idx = t + it * 256;
    if (idx < 640) {
      const int row = idx / 40, oct = idx - row * 40;
      const float4 v0 = *(const float4*)&ctx[(row0 + row) * 320 + oct * 8];
      const float4 v1 = *(const float4*)&ctx[(row0 + row) * 320 + oct * 8 + 4];
      ushort4* dst = (ushort4*)&s_c[(oct * 16 + row) * 8];
      dst[0] = make_ushort4(f2bf(v0.x), f2bf(v0.y), f2bf(v0.z), f2bf(v0.w));
      dst[1] = make_ushort4(f2bf(v1.x), f2bf(v1.y), f2bf(v1.z), f2bf(v1.w));
    }
  }
  __syncthreads();

  const int w = t >> 6, l = t & 63, lg = l >> 4, lr = l & 15;
  f32x4 acc[5];
#pragma unroll
  for (int u = 0; u < 5; ++u) acc[u] = (f32x4){0.f, 0.f, 0.f, 0.f};
#pragma unroll
  for (int ks = 0; ks < 10; ++ks) {
    const bf16x8 afr = *(const bf16x8*)&s_c[((ks * 4 + lg) * 16 + lr) * 8];
    bf16x8 bfr[5];
#pragma unroll
    for (int u = 0; u < 5; ++u)
      bfr[u] = *(const bf16x8*)&Bf[(((ks * 4 + lg) * 640) + half * 320 +
                                    w * 80 + u * 16 + lr) * 8];
#pragma unroll
    for (int u = 0; u < 5; ++u)
      acc[u] = __builtin_amdgcn_mfma_f32_16x16x32_bf16(afr, bfr[u], acc[u], 0, 0, 0);
  }
#pragma unroll
  for (int u = 0; u < 5; ++u) {
    const int n = w * 80 + u * 16 + lr;
    const float bias = (half == 0) ? b1[n] : 0.0f;
    float* dst = (half == 0) ? P : Q;
#pragma unroll
    for (int r = 0; r < 4; ++r) {
      const int row = row0 + lg * 4 + r;
      dst[row * 320 + n] = acc[u][r] + bias;
    }
  }
}

// ---------------------------------------------------------------------------
// K3: edge MLP (layer1 rank-reduced + layer2 via MFMA) + masked mean, fused.
// grid 512 (one block per (b,i)), block 256 = 4 waves.
// ---------------------------------------------------------------------------
__global__ __launch_bounds__(256)
void k_edge(const float* __restrict__ P, const float* __restrict__ Q,
            const float* __restrict__ pos, const float* __restrict__ W1,
            const unsigned short* __restrict__ Bf, const float* __restrict__ b2,
            float* __restrict__ agg) {
  __shared__ __align__(16) unsigned short s_A[40 * 64 * 8];  // 40 KB
  const int bx = blockIdx.x;
  const int b = bx >> 6, i = bx & 63;
  const int t = threadIdx.x;
  const int w = t >> 6, l = t & 63;

  {
    const int j = t & 63;
    const int sub = t >> 6;
    const float2 pi = *(const float2*)&pos[b * 128 + 2 * i];
    const float2 pj = *(const float2*)&pos[b * 128 + 2 * j];
    const float rx = pi.x - pj.x, ry = pi.y - pj.y;
    const float* __restrict__ Prow = P + bx * 320;
    const float* __restrict__ Qrow = Q + (b * 64 + j) * 320;
    const float* __restrict__ w0 = W1 + 640 * 320;
    const float* __restrict__ w1 = W1 + 641 * 320;
#pragma unroll
    for (int g = 0; g < 10; ++g) {
      const int k0 = g * 32 + sub * 8;
      const float4 p0 = *(const float4*)&Prow[k0];
      const float4 p1 = *(const float4*)&Prow[k0 + 4];
      const float4 q0 = *(const float4*)&Qrow[k0];
      const float4 q1 = *(const float4*)&Qrow[k0 + 4];
      const float4 a0 = *(const float4*)&w0[k0];
      const float4 a1 = *(const float4*)&w0[k0 + 4];
      const float4 c0 = *(const float4*)&w1[k0];
      const float4 c1 = *(const float4*)&w1[k0 + 4];
      float v[8];
      v[0] = fmaf(ry, c0.x, fmaf(rx, a0.x, p0.x + q0.x));
      v[1] = fmaf(ry, c0.y, fmaf(rx, a0.y, p0.y + q0.y));
      v[2] = fmaf(ry, c0.z, fmaf(rx, a0.z, p0.z + q0.z));
      v[3] = fmaf(ry, c0.w, fmaf(rx, a0.w, p0.w + q0.w));
      v[4] = fmaf(ry, c1.x, fmaf(rx, a1.x, p1.x + q1.x));
      v[5] = fmaf(ry, c1.y, fmaf(rx, a1.y, p1.y + q1.y));
      v[6] = fmaf(ry, c1.z, fmaf(rx, a1.z, p1.z + q1.z));
      v[7] = fmaf(ry, c1.w, fmaf(rx, a1.w, p1.w + q1.w));
      unsigned short u[8];
#pragma unroll
      for (int e = 0; e < 8; ++e) u[e] = f2bf(fmaxf(v[e], 0.0f));
      ushort4* dst = (ushort4*)&s_A[((g * 4 + sub) * 64 + j) * 8];
      dst[0] = make_ushort4(u[0], u[1], u[2], u[3]);
      dst[1] = make_ushort4(u[4], u[5], u[6], u[7]);
    }
  }
  __syncthreads();

  f32x4 acc[4][5];
#pragma unroll
  for (int mt = 0; mt < 4; ++mt)
#pragma unroll
    for (int u = 0; u < 5; ++u) acc[mt][u] = (f32x4){0.f, 0.f, 0.f, 0.f};

  const int lg = l >> 4, lr = l & 15;
  const unsigned short* __restrict__ Bbase = Bf + (lg * 320 + w * 80 + lr) * 8;
  const unsigned short* __restrict__ Abase = s_A + lg * 512 + lr * 8;

#pragma unroll 2
  for (int ks = 0; ks < 10; ++ks) {
    bf16x8 afr[4];
#pragma unroll
    for (int mt = 0; mt < 4; ++mt)
      afr[mt] = *(const bf16x8*)(Abase + ks * 2048 + mt * 128);
    bf16x8 bfr[5];
#pragma unroll
    for (int u = 0; u < 5; ++u)
      bfr[u] = *(const bf16x8*)(Bbase + ks * 10240 + u * 128);
#pragma unroll
    for (int mt = 0; mt < 4; ++mt)
#pragma unroll
      for (int u = 0; u < 5; ++u)
        acc[mt][u] = __builtin_amdgcn_mfma_f32_16x16x32_bf16(
            afr[mt], bfr[u], acc[mt][u], 0, 0, 0);
  }

#pragma unroll
  for (int u = 0; u < 5; ++u) {
    const int n = w * 80 + u * 16 + lr;
    const float bias = b2[n];
    float p = 0.0f;
#pragma unroll
    for (int mt = 0; mt < 4; ++mt) {
#pragma unroll
      for (int r = 0; r < 4; ++r) {
        const int j = mt * 16 + lg * 4 + r;
        const float e = fmaxf(acc[mt][u][r] + bias, 0.0f);
        p += (j != i) ? e : 0.0f;
      }
    }
    p += __shfl_xor(p, 16);
    p += __shfl_xor(p, 32);
    if (l < 16) agg[bx * 320 + n] = p * (1.0f / 63.0f);
  }
}

// ---------------------------------------------------------------------------
// K4: GRUCell via MFMA, fused pointwise.
// grid 160 = (row-block 32) x (d-block 5); block 256 = 4 waves; 16 rows/blk.
// ---------------------------------------------------------------------------
__global__ __launch_bounds__(256)
void k_gruM(const float* __restrict__ ctx, const float* __restrict__ agg,
            const unsigned short* __restrict__ BfI,
            const unsigned short* __restrict__ BfH,
            const float* __restrict__ bih, const float* __restrict__ bhh,
            float* __restrict__ h) {
  __shared__ __align__(16) unsigned short s_x[80 * 16 * 8];  // 20 KB
  const int rb = blockIdx.x / 5, db = blockIdx.x % 5;
  const int row0 = rb * 16, d0 = db * 64;
  const int t = threadIdx.x;

  // stage x = [ctx | agg] rows -> bf16 fragment layout (1280 octets)
#pragma unroll
  for (int it = 0; it < 5; ++it) {
    const int idx = t + it * 256;
    const int row = idx / 80, oct = idx - row * 80;
    float4 v0, v1;
    if (oct < 40) {
      v0 = *(const float4*)&ctx[(row0 + row) * 320 + oct * 8];
      v1 = *(const float4*)&ctx[(row0 + row) * 320 + oct * 8 + 4];
    } else {
      v0 = *(const float4*)&agg[(row0 + row) * 320 + (oct - 40) * 8];
      v1 = *(const float4*)&agg[(row0 + row) * 320 + (oct - 40) * 8 + 4];
    }
    ushort4* dst = (ushort4*)&s_x[(oct * 16 + row) * 8];
    dst[0] = make_ushort4(f2bf(v0.x), f2bf(v0.y), f2bf(v0.z), f2bf(v0.w));
    dst[1] = make_ushort4(f2bf(v1.x), f2bf(v1.y), f2bf(v1.z), f2bf(v1.w));
  }
  __syncthreads();

  const int w = t >> 6, l = t & 63, lg = l >> 4, lr = l & 15;
  const int d = d0 + w * 16 + lr;

  f32x4 accI[3], accH[3];
#pragma unroll
  for (int g = 0; g < 3; ++g) {
    accI[g] = (f32x4){0.f, 0.f, 0.f, 0.f};
    accH[g] = (f32x4){0.f, 0.f, 0.f, 0.f};
  }

#pragma unroll 2
  for (int ks = 0; ks < 20; ++ks) {
    const bf16x8 afr = *(const bf16x8*)&s_x[((ks * 4 + lg) * 16 + lr) * 8];
    bf16x8 bfr[3];
#pragma unroll
    for (int g = 0; g < 3; ++g)
      bfr[g] = *(const bf16x8*)&BfI[((ks * 4 + lg) * 960 + g * 320 + d) * 8];
#pragma unroll
    for (int g = 0; g < 3; ++g)
      accI[g] = __builtin_amdgcn_mfma_f32_16x16x32_bf16(afr, bfr[g], accI[g], 0, 0, 0);
  }
#pragma unroll 2
  for (int ks = 0; ks < 10; ++ks) {
    const bf16x8 afr = *(const bf16x8*)&s_x[((ks * 4 + lg) * 16 + lr) * 8];
    bf16x8 bfr[3];
#pragma unroll
    for (int g = 0; g < 3; ++g)
      bfr[g] = *(const bf16x8*)&BfH[((ks * 4 + lg) * 960 + g * 320 + d) * 8];
#pragma unroll
    for (int g = 0; g < 3; ++g)
      accH[g] = __builtin_amdgcn_mfma_f32_16x16x32_bf16(afr, bfr[g], accH[g], 0, 0, 0);
  }

  const float b_ir = bih[d], b_iz = bih[320 + d], b_in = bih[640 + d];
  const float b_hr = bhh[d], b_hz = bhh[320 + d], b_hn = bhh[640 + d];
#pragma unroll
  for (int r = 0; r < 4; ++r) {
    const int row = row0 + lg * 4 + r;
    const float ir = accI[0][r] + b_ir;
    const float iz = accI[1][r] + b_iz;
    const float inn = accI[2][r] + b_in;
    const float hr = accH[0][r] + b_hr;
    const float hz = accH[1][r] + b_hz;
    const float hn = accH[2][r] + b_hn;
    const float rr = 1.0f / (1.0f + expf(-(ir + hr)));
    const float zz = 1.0f / (1.0f + expf(-(iz + hz)));
    const float nn = tanhf(fmaf(rr, hn, inn));
    const float c = ctx[row * 320 + d];
    h[row * 320 + d] = (1.0f - zz) * nn + zz * c;
  }
}

// ---------------------------------------------------------------------------
// K5a: mode head via MFMA + fused softmax.  grid 16, block 256 = 4 waves.
// GEMM1 (320x320) -> relu -> GEMM2 (320x6, W2 zero-padded to 16 cols).
// ---------------------------------------------------------------------------
__global__ __launch_bounds__(256)
void k_modeM(const float* __restrict__ h, const unsigned short* __restrict__ B1,
             const float* __restrict__ b1, const unsigned short* __restrict__ B2,
             const float* __restrict__ b2, float* __restrict__ out) {
  __shared__ __align__(16) unsigned short s_h[40 * 32 * 8];  // 20 KB
  __shared__ __align__(16) unsigned short s_t[40 * 32 * 8];  // 20 KB
  __shared__ float s_l[32][6];
  const int row0 = blockIdx.x * 32;
  const int t = threadIdx.x;

#pragma unroll
  for (int it = 0; it < 5; ++it) {
    const int idx = t + it * 256;
    const int row = idx / 40, oct = idx - row * 40;
    const float4 v0 = *(const float4*)&h[(row0 + row) * 320 + oct * 8];
    const float4 v1 = *(const float4*)&h[(row0 + row) * 320 + oct * 8 + 4];
    ushort4* dst = (ushort4*)&s_h[(oct * 32 + row) * 8];
    dst[0] = make_ushort4(f2bf(v0.x), f2bf(v0.y), f2bf(v0.z), f2bf(v0.w));
    dst[1] = make_ushort4(f2bf(v1.x), f2bf(v1.y), f2bf(v1.z), f2bf(v1.w));
  }
  __syncthreads();

  const int w = t >> 6, l = t & 63, lg = l >> 4, lr = l & 15;

  // GEMM1
  f32x4 acc1[2][5];
#pragma unroll
  for (int mt = 0; mt < 2; ++mt)
#pragma unroll
    for (int u = 0; u < 5; ++u) acc1[mt][u] = (f32x4){0.f, 0.f, 0.f, 0.f};
#pragma unroll
  for (int ks = 0; ks < 10; ++ks) {
    bf16x8 afr[2];
#pragma unroll
    for (int mt = 0; mt < 2; ++mt)
      afr[mt] = *(const bf16x8*)&s_h[(((ks * 4 + lg) * 32) + mt * 16 + lr) * 8];
    bf16x8 bfr[5];
#pragma unroll
    for (int u = 0; u < 5; ++u)
      bfr[u] = *(const bf16x8*)&B1[((ks * 4 + lg) * 320 + w * 80 + u * 16 + lr) * 8];
#pragma unroll
    for (int mt = 0; mt < 2; ++mt)
#pragma unroll
      for (int u = 0; u < 5; ++u)
        acc1[mt][u] = __builtin_amdgcn_mfma_f32_16x16x32_bf16(
            afr[mt], bfr[u], acc1[mt][u], 0, 0, 0);
  }
#pragma unroll
  for (int u = 0; u < 5; ++u) {
    const int n = w * 80 + u * 16 + lr;
    const float bias = b1[n];
#pragma unroll
    for (int mt = 0; mt < 2; ++mt) {
#pragma unroll
      for (int r = 0; r < 4; ++r) {
        const int row = mt * 16 + lg * 4 + r;
        s_t[((n >> 3) * 32 + row) * 8 + (n & 7)] =
            f2bf(fmaxf(acc1[mt][u][r] + bias, 0.0f));
      }
    }
  }
  __syncthreads();

  // GEMM2: waves 0,1 (m-tile = w); cols 0..5 valid
  if (w < 2) {
    f32x4 acc2 = (f32x4){0.f, 0.f, 0.f, 0.f};
#pragma unroll
    for (int ks = 0; ks < 10; ++ks) {
      const bf16x8 afr = *(const bf16x8*)&s_t[(((ks * 4 + lg) * 32) + w * 16 + lr) * 8];
      const bf16x8 bfr = *(const bf16x8*)&B2[((ks * 4 + lg) * 16 + lr) * 8];
      acc2 = __builtin_amdgcn_mfma_f32_16x16x32_bf16(afr, bfr, acc2, 0, 0, 0);
    }
    if (lr < 6) {
#pragma unroll
      for (int r = 0; r < 4; ++r)
        s_l[w * 16 + lg * 4 + r][lr] = acc2[r] + b2[lr];
    }
  }
  __syncthreads();

  if (t < 32) {
    float v[6];
#pragma unroll
    for (int q = 0; q < 6; ++q) v[q] = s_l[t][q];
    float mx = v[0];
#pragma unroll
    for (int q = 1; q < 6; ++q) mx = fmaxf(mx, v[q]);
    float sum = 0.0f;
#pragma unroll
    for (int q = 0; q < 6; ++q) { v[q] = expf(v[q] - mx); sum += v[q]; }
    const float inv = 1.0f / sum;
#pragma unroll
    for (int q = 0; q < 6; ++q) out[491520 + (row0 + t) * 6 + q] = v[q] * inv;
  }
}

// ---------------------------------------------------------------------------
// K5b: trajectory head via MFMA, both GEMMs fused (all bounds compile-time).
// grid (32, 6); block 256 = 4 waves; rows [rb*16,+16), mode m.
// ---------------------------------------------------------------------------
__global__ __launch_bounds__(256)
void k_trajM(const float* __restrict__ h, const unsigned short* __restrict__ B1,
             const float* __restrict__ b1, const unsigned short* __restrict__ B2,
             const float* __restrict__ b2, float* __restrict__ out) {
  __shared__ __align__(16) unsigned short s_h[40 * 16 * 8];  // 10 KB
  __shared__ __align__(16) unsigned short s_t[40 * 16 * 8];  // 10 KB
  const int rb = blockIdx.x, m = blockIdx.y;
  const int row0 = rb * 16;
  const int t = threadIdx.x;

#pragma unroll
  for (int it = 0; it < 3; ++it) {
    const int idx = t + it * 256;
    if (idx < 640) {
      const int row = idx / 40, oct = idx - row * 40;
      const float4 v0 = *(const float4*)&h[(row0 + row) * 320 + oct * 8];
      const float4 v1 = *(const float4*)&h[(row0 + row) * 320 + oct * 8 + 4];
      ushort4* dst = (ushort4*)&s_h[(oct * 16 + row) * 8];
      dst[0] = make_ushort4(f2bf(v0.x), f2bf(v0.y), f2bf(v0.z), f2bf(v0.w));
      dst[1] = make_ushort4(f2bf(v1.x), f2bf(v1.y), f2bf(v1.z), f2bf(v1.w));
    }
  }
  __syncthreads();

  const int w = t >> 6, l = t & 63, lg = l >> 4, lr = l & 15;

  f32x4 acc1[5];
#pragma unroll
  for (int u = 0; u < 5; ++u) acc1[u] = (f32x4){0.f, 0.f, 0.f, 0.f};
  const unsigned short* __restrict__ B1m = B1 + m * 102400;
#pragma unroll
  for (int ks = 0; ks < 10; ++ks) {
    const bf16x8 afr = *(const bf16x8*)&s_h[((ks * 4 + lg) * 16 + lr) * 8];
    bf16x8 bfr[5];
#pragma unroll
    for (int u = 0; u < 5; ++u)
      bfr[u] = *(const bf16x8*)&B1m[((ks * 4 + lg) * 320 + w * 80 + u * 16 + lr) * 8];
#pragma unroll
    for (int u = 0; u < 5; ++u)
      acc1[u] = __builtin_amdgcn_mfma_f32_16x16x32_bf16(afr, bfr[u], acc1[u], 0, 0, 0);
  }
#pragma unroll
  for (int u = 0; u < 5; ++u) {
    const int n = w * 80 + u * 16 + lr;
    const float bias = b1[m * 320 + n];
#pragma unroll
    for (int r = 0; r < 4; ++r) {
      const int row = lg * 4 + r;
      s_t[((n >> 3) * 16 + row) * 8 + (n & 7)] =
          f2bf(fmaxf(acc1[u][r] + bias, 0.0f));
    }
  }
  __syncthreads();

  const int nb = (w == 0) ? 0 : (w == 1) ? 3 : (w == 2) ? 6 : 7;
  f32x4 acc2[3];
#pragma unroll
  for (int u = 0; u < 3; ++u) acc2[u] = (f32x4){0.f, 0.f, 0.f, 0.f};
  const unsigned short* __restrict__ B2m = B2 + m * 51200;
#pragma unroll
  for (int ks = 0; ks < 10; ++ks) {
    const bf16x8 afr = *(const bf16x8*)&s_t[((ks * 4 + lg) * 16 + lr) * 8];
    bf16x8 bfr[3];
#pragma unroll
    for (int u = 0; u < 3; ++u)
      bfr[u] = *(const bf16x8*)&B2m[((ks * 4 + lg) * 160 + (nb + u) * 16 + lr) * 8];
#pragma unroll
    for (int u = 0; u < 3; ++u)
      acc2[u] = __builtin_amdgcn_mfma_f32_16x16x32_bf16(afr, bfr[u], acc2[u], 0, 0, 0);
  }
#pragma unroll
  for (int u = 0; u < 3; ++u) {
    const int n = (nb + u) * 16 + lr;
    const float bias = b2[m * 160 + n];
#pragma unroll
    for (int r = 0; r < 4; ++r) {
      const int row = row0 + lg * 4 + r;
      out[(row * 6 + m) * 160 + n] = acc2[u][r] + bias;
    }
  }
}

// ---------------------------------------------------------------------------
extern "C" void kernel_launch(void* const* d_in, const int* in_sizes, int n_in,
                              void* d_out, int out_size, void* d_ws, size_t ws_size,
                              hipStream_t stream) {
  (void)in_sizes; (void)n_in; (void)out_size; (void)ws_size;
  const float* feat  = (const float*)d_in[0];
  const float* attr  = (const float*)d_in[1];
  const float* pos   = (const float*)d_in[3];
  const float* encW1 = (const float*)d_in[4];
  const float* encb1 = (const float*)d_in[5];
  const float* encW2 = (const float*)d_in[6];
  const float* encb2 = (const float*)d_in[7];
  const float* edgW1 = (const float*)d_in[12];
  const float* edgb1 = (const float*)d_in[13];
  const float* edgW2 = (const float*)d_in[14];
  const float* edgb2 = (const float*)d_in[15];
  const float* Wih   = (const float*)d_in[16];
  const float* Whh   = (const float*)d_in[17];
  const float* bih   = (const float*)d_in[18];
  const float* bhh   = (const float*)d_in[19];
  const float* mW1   = (const float*)d_in[20];
  const float* mb1   = (const float*)d_in[21];
  const float* mW2   = (const float*)d_in[22];
  const float* mb2   = (const float*)d_in[23];
  const float* tW1   = (const float*)d_in[24];
  const float* tb1   = (const float*)d_in[25];
  const float* tW2   = (const float*)d_in[26];
  const float* tb2   = (const float*)d_in[27];

  float* out = (float*)d_out;
  float* ws  = (float*)d_ws;
  float* ctx  = ws;                       // 512*320
  float* P    = ws + 163840;
  float* Q    = ws + 327680;
  float* agg  = ws + 491520;
  float* hbuf = ws + 655360;
  unsigned short* ub = (unsigned short*)(ws + 819200);
  unsigned short* W2bf  = ub;             // 102400 u
  unsigned short* WihBf = ub + 102400;    // 614400 u
  unsigned short* WhhBf = ub + 716800;    // 307200 u
  unsigned short* T1bf  = ub + 1024000;   // 614400 u
  unsigned short* T2bf  = ub + 1638400;   // 307200 u
  unsigned short* EW1bf = ub + 1945600;   // 204800 u
  unsigned short* MW1bf = ub + 2150400;   // 102400 u
  unsigned short* MW2bf = ub + 2252800;   // 5120 u (padded N=16)

  k_cvt<<<1103, 256, 0, stream>>>(edgW2, Wih, Whh, tW1, tW2, edgW1, mW1, mW2, ub);
  k_encoder<<<128, 256, 0, stream>>>(feat, attr, encW1, encb1, encW2, encb2, ctx);
  k_pqM<<<dim3(32, 2), 256, 0, stream>>>(ctx, EW1bf, edgb1, P, Q);
  k_edge<<<512, 256, 0, stream>>>(P, Q, pos, edgW1, W2bf, edgb2, agg);
  k_gruM<<<160, 256, 0, stream>>>(ctx, agg, WihBf, WhhBf, bih, bhh, hbuf);
  k_modeM<<<16, 256, 0, stream>>>(hbuf, MW1bf, mb1, MW2bf, mb2, out);
  k_trajM<<<dim3(32, 6), 256, 0, stream>>>(hbuf, T1bf, tb1, T2bf, tb2, out);
}

// Round 6
// 78.034 us; speedup vs baseline: 5.5760x; 1.1210x over previous
//
#include <hip/hip_runtime.h>

// ---------------------------------------------------------------------------
// Sizes: B=8, N=64, FD=128, HD=256, MD=64, D=320, NM=6, FS=80, rows=B*N=512
// ---------------------------------------------------------------------------

typedef __attribute__((ext_vector_type(8))) short bf16x8;   // 8 bf16 (4 VGPR)
typedef __attribute__((ext_vector_type(4))) float f32x4;

__device__ __forceinline__ unsigned short f2bf(float x) {   // RNE f32->bf16
  unsigned u = __float_as_uint(x);
  return (unsigned short)((u + 0x7fffu + ((u >> 16) & 1u)) >> 16);
}

// ---- JAX threefry2x32 (20 rounds), key = [0, 42] ---------------------------
__device__ __forceinline__ void threefry2x32(unsigned k0, unsigned k1,
                                             unsigned& x0, unsigned& x1) {
  const unsigned ks0 = k0, ks1 = k1, ks2 = k0 ^ k1 ^ 0x1BD11BDAu;
  x0 += ks0; x1 += ks1;
#define TFR(r) { x0 += x1; x1 = (x1 << (r)) | (x1 >> (32 - (r))); x1 ^= x0; }
  TFR(13) TFR(15) TFR(26) TFR(6)  x0 += ks1; x1 += ks2 + 1u;
  TFR(17) TFR(29) TFR(16) TFR(24) x0 += ks2; x1 += ks0 + 2u;
  TFR(13) TFR(15) TFR(26) TFR(6)  x0 += ks0; x1 += ks1 + 3u;
  TFR(17) TFR(29) TFR(16) TFR(24) x0 += ks1; x1 += ks2 + 4u;
  TFR(13) TFR(15) TFR(26) TFR(6)  x0 += ks2; x1 += ks0 + 5u;
#undef TFR
}

__device__ __forceinline__ float erfinv_xla(float x) {
  float w = -logf((1.0f - x) * (1.0f + x));
  float p;
  if (w < 5.0f) {
    w = w - 2.5f;
    p = 2.81022636e-08f;
    p = fmaf(p, w, 3.43273939e-07f);
    p = fmaf(p, w, -3.5233877e-06f);
    p = fmaf(p, w, -4.39150654e-06f);
    p = fmaf(p, w, 0.00021858087f);
    p = fmaf(p, w, -0.00125372503f);
    p = fmaf(p, w, -0.00417768164f);
    p = fmaf(p, w, 0.246640727f);
    p = fmaf(p, w, 1.50140941f);
  } else {
    w = sqrtf(w) - 3.0f;
    p = -0.000200214257f;
    p = fmaf(p, w, 0.000100950558f);
    p = fmaf(p, w, 0.00134934322f);
    p = fmaf(p, w, -0.00367342844f);
    p = fmaf(p, w, 0.00573950773f);
    p = fmaf(p, w, -0.0076224613f);
    p = fmaf(p, w, 0.00943887047f);
    p = fmaf(p, w, 1.00167406f);
    p = fmaf(p, w, 2.83297682f);
  }
  return p * x;
}

__device__ __forceinline__ float jax_normal42(unsigned idx) {
  unsigned x0 = 0u, x1 = idx;
  threefry2x32(0u, 42u, x0, x1);
  unsigned bits = x0 ^ x1;
  float f = __uint_as_float((bits >> 9) | 0x3f800000u) - 1.0f;
  const float lo = -0.99999994f;
  float u = fmaxf(lo, f * 2.0f + lo);
  return 1.41421356237f * erfinv_xla(u);
}

// ---------------------------------------------------------------------------
// K_head = cvt (blocks 0..1102) + encoder (blocks 1103..1230), independent.
// cvt: f32 -> bf16 fragment layout [k>>3][n][k&7], 282240 octets.
// ---------------------------------------------------------------------------
__global__ __launch_bounds__(256)
void k_head(const float* __restrict__ W2e, const float* __restrict__ Wih,
            const float* __restrict__ Whh, const float* __restrict__ T1,
            const float* __restrict__ T2, const float* __restrict__ EW1,
            const float* __restrict__ MW1, const float* __restrict__ MW2,
            unsigned short* __restrict__ ub,
            const float* __restrict__ feat, const float* __restrict__ attr,
            const float* __restrict__ eW1, const float* __restrict__ eb1,
            const float* __restrict__ eW2, const float* __restrict__ eb2,
            float* __restrict__ ctx) {
  __shared__ float s_in[4][136];
  __shared__ float s_h1[4][256];
  const int t = threadIdx.x;

  if (blockIdx.x < 1103) {  // ---- weight converter ----
    const int id = blockIdx.x * 256 + t;
    if (id >= 282240) return;
    if (id >= 281600) {  // MW2 padded to 16 cols
      const int rem = id - 281600;
      const int g = rem >> 4, n = rem & 15;
      unsigned short v[8];
#pragma unroll
      for (int e = 0; e < 8; ++e) v[e] = (n < 6) ? f2bf(MW2[(g * 8 + e) * 6 + n]) : 0;
      ushort4* d = (ushort4*)&ub[2252800 + (size_t)rem * 8];
      d[0] = make_ushort4(v[0], v[1], v[2], v[3]);
      d[1] = make_ushort4(v[4], v[5], v[6], v[7]);
      return;
    }
    const float* src;
    unsigned short* dst;
    int rem, N;
    if (id < 12800)       { src = W2e; dst = ub;           rem = id;          N = 320; }
    else if (id < 89600)  { src = Wih; dst = ub + 102400;  rem = id - 12800;  N = 960; }
    else if (id < 128000) { src = Whh; dst = ub + 716800;  rem = id - 89600;  N = 960; }
    else if (id < 204800) { src = T1;  dst = ub + 1024000; rem = id - 128000; N = 320; }
    else if (id < 243200) { src = T2;  dst = ub + 1638400; rem = id - 204800; N = 160; }
    else if (id < 268800) { src = EW1; dst = ub + 1945600; rem = id - 243200; N = 320; }
    else                  { src = MW1; dst = ub + 2150400; rem = id - 268800; N = 320; }
    const int g = rem / N, n = rem - g * N;
    const float* s = src + g * 8 * N + n;
    unsigned short v[8];
#pragma unroll
    for (int e = 0; e < 8; ++e) v[e] = f2bf(s[e * N]);
    ushort4* d = (ushort4*)&dst[(size_t)rem * 8];
    d[0] = make_ushort4(v[0], v[1], v[2], v[3]);
    d[1] = make_ushort4(v[4], v[5], v[6], v[7]);
    return;
  }

  // ---- object encoder: ctx[:,0:256]=emb ; ctx[:,256:320]=sampled ----
  const int r0 = (blockIdx.x - 1103) * 4;
  for (int r = 0; r < 4; ++r) {
    if (t < 128)      s_in[r][t] = feat[(r0 + r) * 128 + t];
    else if (t < 136) s_in[r][t] = attr[(r0 + r) * 8 + (t - 128)];
  }
  __syncthreads();
  float acc[4];
#pragma unroll
  for (int r = 0; r < 4; ++r) acc[r] = eb1[t];
  for (int k = 0; k < 136; ++k) {
    const float w = eW1[k * 256 + t];
#pragma unroll
    for (int r = 0; r < 4; ++r) acc[r] = fmaf(s_in[r][k], w, acc[r]);
  }
#pragma unroll
  for (int r = 0; r < 4; ++r) s_h1[r][t] = fmaxf(acc[r], 0.0f);
  __syncthreads();
#pragma unroll
  for (int r = 0; r < 4; ++r) acc[r] = eb2[t];
  for (int k = 0; k < 256; ++k) {
    const float w = eW2[k * 256 + t];
#pragma unroll
    for (int r = 0; r < 4; ++r) acc[r] = fmaf(s_h1[r][k], w, acc[r]);
  }
#pragma unroll
  for (int r = 0; r < 4; ++r) ctx[(r0 + r) * 320 + t] = fmaxf(acc[r], 0.0f);
  if (t < 64) {
    for (int r = 0; r < 4; ++r)
      ctx[(r0 + r) * 320 + 256 + t] = jax_normal42((unsigned)((r0 + r) * 64 + t));
  }
}

// ---------------------------------------------------------------------------
// K2: P/Q via MFMA.  grid (32 rb, 2 half), block 256 = 4 waves.
// ---------------------------------------------------------------------------
__global__ __launch_bounds__(256)
void k_pqM(const float* __restrict__ ctx, const unsigned short* __restrict__ Bf,
           const float* __restrict__ b1, float* __restrict__ P,
           float* __restrict__ Q) {
  __shared__ __align__(16) unsigned short s_c[40 * 16 * 8];  // 10 KB
  const int row0 = blockIdx.x * 16;
  const int half = blockIdx.y;
  const int t = threadIdx.x;
#pragma unroll
  for (int it = 0; it < 3; ++it) {
    const int idx = t + it * 256;
    if (idx < 640) {
      const int row = idx / 40, oct = idx - row * 40;
      const float4 v0 = *(const float4*)&ctx[(row0 + row) * 320 + oct * 8];
      const float4 v1 = *(const float4*)&ctx[(row0 + row) * 320 + oct * 8 + 4];
      ushort4* dst = (ushort4*)&s_c[(oct * 16 + row) * 8];
      dst[0] = make_ushort4(f2bf(v0.x), f2bf(v0.y), f2bf(v0.z), f2bf(v0.w));
      dst[1] = make_ushort4(f2bf(v1.x), f2bf(v1.y), f2bf(v1.z), f2bf(v1.w));
    }
  }
  __syncthreads();

  const int w = t >> 6, l = t & 63, lg = l >> 4, lr = l & 15;
  f32x4 acc[5];
#pragma unroll
  for (int u = 0; u < 5; ++u) acc[u] = (f32x4){0.f, 0.f, 0.f, 0.f};
#pragma unroll
  for (int ks = 0; ks < 10; ++ks) {
    const bf16x8 afr = *(const bf16x8*)&s_c[((ks * 4 + lg) * 16 + lr) * 8];
    bf16x8 bfr[5];
#pragma unroll
    for (int u = 0; u < 5; ++u)
      bfr[u] = *(const bf16x8*)&Bf[(((ks * 4 + lg) * 640) + half * 320 +
                                    w * 80 + u * 16 + lr) * 8];
#pragma unroll
    for (int u = 0; u < 5; ++u)
      acc[u] = __builtin_amdgcn_mfma_f32_16x16x32_bf16(afr, bfr[u], acc[u], 0, 0, 0);
  }
#pragma unroll
  for (int u = 0; u < 5; ++u) {
    const int n = w * 80 + u * 16 + lr;
    const float bias = (half == 0) ? b1[n] : 0.0f;
    float* dst = (half == 0) ? P : Q;
#pragma unroll
    for (int r = 0; r < 4; ++r) {
      const int row = row0 + lg * 4 + r;
      dst[row * 320 + n] = acc[u][r] + bias;
    }
  }
}

// ---------------------------------------------------------------------------
// K3: edge MLP + masked mean, fused.  grid 512 (one block per (b,i)), 4 waves.
// Phase A: COALESCED task mapping tau=(wave*640+it*64+lane) -> (j=tau/40,
// oct=tau%40): consecutive lanes read consecutive 32B of one Q row.
// LDS fragment store XOR-swizzled (elem ^= (oct&7)<<3) to break the
// resulting 40-way bank aliasing; fragment reads apply the same XOR.
// Values are bit-identical to the unswizzled version.
// ---------------------------------------------------------------------------
__global__ __launch_bounds__(256)
void k_edge(const float* __restrict__ P, const float* __restrict__ Q,
            const float* __restrict__ pos, const float* __restrict__ W1,
            const unsigned short* __restrict__ Bf, const float* __restrict__ b2,
            float* __restrict__ agg) {
  __shared__ __align__(16) unsigned short s_A[40 * 64 * 8];  // 40 KB
  const int bx = blockIdx.x;
  const int b = bx >> 6, i = bx & 63;
  const int t = threadIdx.x;
  const int w = t >> 6, l = t & 63;

  // ---- phase A: h1 -> s_A (bf16, swizzled fragment layout) ----
  {
    const float2 pi = *(const float2*)&pos[b * 128 + 2 * i];
    const float* __restrict__ Prow = P + bx * 320;
    const float* __restrict__ w0 = W1 + 640 * 320;
    const float* __restrict__ w1 = W1 + 641 * 320;
#pragma unroll
    for (int it = 0; it < 10; ++it) {
      const int tau = w * 640 + it * 64 + l;
      const int j = tau / 40;
      const int oct = tau - j * 40;
      const int k0 = oct * 8;
      const float2 pj = *(const float2*)&pos[b * 128 + 2 * j];
      const float rx = pi.x - pj.x, ry = pi.y - pj.y;
      const float* __restrict__ Qrow = Q + (b * 64 + j) * 320;
      const float4 q0 = *(const float4*)&Qrow[k0];
      const float4 q1 = *(const float4*)&Qrow[k0 + 4];
      const float4 p0 = *(const float4*)&Prow[k0];
      const float4 p1 = *(const float4*)&Prow[k0 + 4];
      const float4 a0 = *(const float4*)&w0[k0];
      const float4 a1 = *(const float4*)&w0[k0 + 4];
      const float4 c0 = *(const float4*)&w1[k0];
      const float4 c1 = *(const float4*)&w1[k0 + 4];
      float v[8];
      v[0] = fmaf(ry, c0.x, fmaf(rx, a0.x, p0.x + q0.x));
      v[1] = fmaf(ry, c0.y, fmaf(rx, a0.y, p0.y + q0.y));
      v[2] = fmaf(ry, c0.z, fmaf(rx, a0.z, p0.z + q0.z));
      v[3] = fmaf(ry, c0.w, fmaf(rx, a0.w, p0.w + q0.w));
      v[4] = fmaf(ry, c1.x, fmaf(rx, a1.x, p1.x + q1.x));
      v[5] = fmaf(ry, c1.y, fmaf(rx, a1.y, p1.y + q1.y));
      v[6] = fmaf(ry, c1.z, fmaf(rx, a1.z, p1.z + q1.z));
      v[7] = fmaf(ry, c1.w, fmaf(rx, a1.w, p1.w + q1.w));
      unsigned short u[8];
#pragma unroll
      for (int e = 0; e < 8; ++e) u[e] = f2bf(fmaxf(v[e], 0.0f));
      const int swz = ((oct * 64 + j) * 8) ^ ((oct & 7) << 3);
      *(ushort4*)&s_A[swz]     = make_ushort4(u[0], u[1], u[2], u[3]);
      *(ushort4*)&s_A[swz + 4] = make_ushort4(u[4], u[5], u[6], u[7]);
    }
  }
  __syncthreads();

  // ---- phase B: C = A @ B via MFMA ----
  f32x4 acc[4][5];
#pragma unroll
  for (int mt = 0; mt < 4; ++mt)
#pragma unroll
    for (int u = 0; u < 5; ++u) acc[mt][u] = (f32x4){0.f, 0.f, 0.f, 0.f};

  const int lg = l >> 4, lr = l & 15;
  const unsigned short* __restrict__ Bbase = Bf + (lg * 320 + w * 80 + lr) * 8;

#pragma unroll 2
  for (int ks = 0; ks < 10; ++ks) {
    const int oct = ks * 4 + lg;
    bf16x8 afr[4];
#pragma unroll
    for (int mt = 0; mt < 4; ++mt) {
      const int elem = ((oct * 64 + mt * 16 + lr) * 8) ^ ((oct & 7) << 3);
      afr[mt] = *(const bf16x8*)&s_A[elem];
    }
    bf16x8 bfr[5];
#pragma unroll
    for (int u = 0; u < 5; ++u)
      bfr[u] = *(const bf16x8*)(Bbase + ks * 10240 + u * 128);
#pragma unroll
    for (int mt = 0; mt < 4; ++mt)
#pragma unroll
      for (int u = 0; u < 5; ++u)
        acc[mt][u] = __builtin_amdgcn_mfma_f32_16x16x32_bf16(
            afr[mt], bfr[u], acc[mt][u], 0, 0, 0);
  }

  // ---- epilogue: +b2, relu, masked sum over j != i, /63 ----
#pragma unroll
  for (int u = 0; u < 5; ++u) {
    const int n = w * 80 + u * 16 + lr;
    const float bias = b2[n];
    float p = 0.0f;
#pragma unroll
    for (int mt = 0; mt < 4; ++mt) {
#pragma unroll
      for (int r = 0; r < 4; ++r) {
        const int j = mt * 16 + lg * 4 + r;
        const float e = fmaxf(acc[mt][u][r] + bias, 0.0f);
        p += (j != i) ? e : 0.0f;
      }
    }
    p += __shfl_xor(p, 16);
    p += __shfl_xor(p, 32);
    if (l < 16) agg[bx * 320 + n] = p * (1.0f / 63.0f);
  }
}

// ---------------------------------------------------------------------------
// K4: GRUCell via MFMA, fused pointwise.
// grid 160 = (row-block 32) x (d-block 5); block 256 = 4 waves; 16 rows/blk.
// ---------------------------------------------------------------------------
__global__ __launch_bounds__(256)
void k_gruM(const float* __restrict__ ctx, const float* __restrict__ agg,
            const unsigned short* __restrict__ BfI,
            const unsigned short* __restrict__ BfH,
            const float* __restrict__ bih, const float* __restrict__ bhh,
            float* __restrict__ h) {
  __shared__ __align__(16) unsigned short s_x[80 * 16 * 8];  // 20 KB
  const int rb = blockIdx.x / 5, db = blockIdx.x % 5;
  const int row0 = rb * 16, d0 = db * 64;
  const int t = threadIdx.x;

#pragma unroll
  for (int it = 0; it < 5; ++it) {
    const int idx = t + it * 256;
    const int row = idx / 80, oct = idx - row * 80;
    float4 v0, v1;
    if (oct < 40) {
      v0 = *(const float4*)&ctx[(row0 + row) * 320 + oct * 8];
      v1 = *(const float4*)&ctx[(row0 + row) * 320 + oct * 8 + 4];
    } else {
      v0 = *(const float4*)&agg[(row0 + row) * 320 + (oct - 40) * 8];
      v1 = *(const float4*)&agg[(row0 + row) * 320 + (oct - 40) * 8 + 4];
    }
    ushort4* dst = (ushort4*)&s_x[(oct * 16 + row) * 8];
    dst[0] = make_ushort4(f2bf(v0.x), f2bf(v0.y), f2bf(v0.z), f2bf(v0.w));
    dst[1] = make_ushort4(f2bf(v1.x), f2bf(v1.y), f2bf(v1.z), f2bf(v1.w));
  }
  __syncthreads();

  const int w = t >> 6, l = t & 63, lg = l >> 4, lr = l & 15;
  const int d = d0 + w * 16 + lr;

  f32x4 accI[3], accH[3];
#pragma unroll
  for (int g = 0; g < 3; ++g) {
    accI[g] = (f32x4){0.f, 0.f, 0.f, 0.f};
    accH[g] = (f32x4){0.f, 0.f, 0.f, 0.f};
  }

#pragma unroll 2
  for (int ks = 0; ks < 20; ++ks) {
    const bf16x8 afr = *(const bf16x8*)&s_x[((ks * 4 + lg) * 16 + lr) * 8];
    bf16x8 bfr[3];
#pragma unroll
    for (int g = 0; g < 3; ++g)
      bfr[g] = *(const bf16x8*)&BfI[((ks * 4 + lg) * 960 + g * 320 + d) * 8];
#pragma unroll
    for (int g = 0; g < 3; ++g)
      accI[g] = __builtin_amdgcn_mfma_f32_16x16x32_bf16(afr, bfr[g], accI[g], 0, 0, 0);
  }
#pragma unroll 2
  for (int ks = 0; ks < 10; ++ks) {
    const bf16x8 afr = *(const bf16x8*)&s_x[((ks * 4 + lg) * 16 + lr) * 8];
    bf16x8 bfr[3];
#pragma unroll
    for (int g = 0; g < 3; ++g)
      bfr[g] = *(const bf16x8*)&BfH[((ks * 4 + lg) * 960 + g * 320 + d) * 8];
#pragma unroll
    for (int g = 0; g < 3; ++g)
      accH[g] = __builtin_amdgcn_mfma_f32_16x16x32_bf16(afr, bfr[g], accH[g], 0, 0, 0);
  }

  const float b_ir = bih[d], b_iz = bih[320 + d], b_in = bih[640 + d];
  const float b_hr = bhh[d], b_hz = bhh[320 + d], b_hn = bhh[640 + d];
#pragma unroll
  for (int r = 0; r < 4; ++r) {
    const int row = row0 + lg * 4 + r;
    const float ir = accI[0][r] + b_ir;
    const float iz = accI[1][r] + b_iz;
    const float inn = accI[2][r] + b_in;
    const float hr = accH[0][r] + b_hr;
    const float hz = accH[1][r] + b_hz;
    const float hn = accH[2][r] + b_hn;
    const float rr = 1.0f / (1.0f + expf(-(ir + hr)));
    const float zz = 1.0f / (1.0f + expf(-(iz + hz)));
    const float nn = tanhf(fmaf(rr, hn, inn));
    const float c = ctx[row * 320 + d];
    h[row * 320 + d] = (1.0f - zz) * nn + zz * c;
  }
}

// ---------------------------------------------------------------------------
// K_tail = modeM (blocks 0..15) + trajM (blocks 16..207), independent.
// Shared LDS union: s_buf 40 KB.
// ---------------------------------------------------------------------------
__global__ __launch_bounds__(256)
void k_tail(const float* __restrict__ h, const unsigned short* __restrict__ MB1,
            const float* __restrict__ mb1, const unsigned short* __restrict__ MB2,
            const float* __restrict__ mb2, const unsigned short* __restrict__ TB1,
            const float* __restrict__ tb1, const unsigned short* __restrict__ TB2,
            const float* __restrict__ tb2, float* __restrict__ out) {
  __shared__ __align__(16) unsigned short s_buf[20480];  // 40 KB
  __shared__ float s_l[32][6];
  const int t = threadIdx.x;
  const int w = t >> 6, l = t & 63, lg = l >> 4, lr = l & 15;

  if (blockIdx.x < 16) {
    // ------------------- mode head + softmax (32 rows) -------------------
    unsigned short* s_h = s_buf;           // 40*32*8
    unsigned short* s_t = s_buf + 10240;   // 40*32*8
    const int row0 = blockIdx.x * 32;
#pragma unroll
    for (int it = 0; it < 5; ++it) {
      const int idx = t + it * 256;
      const int row = idx / 40, oct = idx - row * 40;
      const float4 v0 = *(const float4*)&h[(row0 + row) * 320 + oct * 8];
      const float4 v1 = *(const float4*)&h[(row0 + row) * 320 + oct * 8 + 4];
      ushort4* dst = (ushort4*)&s_h[(oct * 32 + row) * 8];
      dst[0] = make_ushort4(f2bf(v0.x), f2bf(v0.y), f2bf(v0.z), f2bf(v0.w));
      dst[1] = make_ushort4(f2bf(v1.x), f2bf(v1.y), f2bf(v1.z), f2bf(v1.w));
    }
    __syncthreads();

    f32x4 acc1[2][5];
#pragma unroll
    for (int mt = 0; mt < 2; ++mt)
#pragma unroll
      for (int u = 0; u < 5; ++u) acc1[mt][u] = (f32x4){0.f, 0.f, 0.f, 0.f};
#pragma unroll
    for (int ks = 0; ks < 10; ++ks) {
      bf16x8 afr[2];
#pragma unroll
      for (int mt = 0; mt < 2; ++mt)
        afr[mt] = *(const bf16x8*)&s_h[(((ks * 4 + lg) * 32) + mt * 16 + lr) * 8];
      bf16x8 bfr[5];
#pragma unroll
      for (int u = 0; u < 5; ++u)
        bfr[u] = *(const bf16x8*)&MB1[((ks * 4 + lg) * 320 + w * 80 + u * 16 + lr) * 8];
#pragma unroll
      for (int mt = 0; mt < 2; ++mt)
#pragma unroll
        for (int u = 0; u < 5; ++u)
          acc1[mt][u] = __builtin_amdgcn_mfma_f32_16x16x32_bf16(
              afr[mt], bfr[u], acc1[mt][u], 0, 0, 0);
    }
#pragma unroll
    for (int u = 0; u < 5; ++u) {
      const int n = w * 80 + u * 16 + lr;
      const float bias = mb1[n];
#pragma unroll
      for (int mt = 0; mt < 2; ++mt) {
#pragma unroll
        for (int r = 0; r < 4; ++r) {
          const int row = mt * 16 + lg * 4 + r;
          s_t[((n >> 3) * 32 + row) * 8 + (n & 7)] =
              f2bf(fmaxf(acc1[mt][u][r] + bias, 0.0f));
        }
      }
    }
    __syncthreads();

    if (w < 2) {
      f32x4 acc2 = (f32x4){0.f, 0.f, 0.f, 0.f};
#pragma unroll
      for (int ks = 0; ks < 10; ++ks) {
        const bf16x8 afr = *(const bf16x8*)&s_t[(((ks * 4 + lg) * 32) + w * 16 + lr) * 8];
        const bf16x8 bfr = *(const bf16x8*)&MB2[((ks * 4 + lg) * 16 + lr) * 8];
        acc2 = __builtin_amdgcn_mfma_f32_16x16x32_bf16(afr, bfr, acc2, 0, 0, 0);
      }
      if (lr < 6) {
#pragma unroll
        for (int r = 0; r < 4; ++r)
          s_l[w * 16 + lg * 4 + r][lr] = acc2[r] + mb2[lr];
      }
    }
    __syncthreads();

    if (t < 32) {
      float v[6];
#pragma unroll
      for (int q = 0; q < 6; ++q) v[q] = s_l[t][q];
      float mx = v[0];
#pragma unroll
      for (int q = 1; q < 6; ++q) mx = fmaxf(mx, v[q]);
      float sum = 0.0f;
#pragma unroll
      for (int q = 0; q < 6; ++q) { v[q] = expf(v[q] - mx); sum += v[q]; }
      const float inv = 1.0f / sum;
#pragma unroll
      for (int q = 0; q < 6; ++q) out[491520 + (row0 + t) * 6 + q] = v[q] * inv;
    }
    return;
  }

  // ------------------- trajectory head (16 rows, one mode) -------------------
  const int idx0 = blockIdx.x - 16;
  const int m = idx0 >> 5, rb = idx0 & 31;
  unsigned short* s_h = s_buf;          // 40*16*8
  unsigned short* s_t = s_buf + 5120;   // 40*16*8
  const int row0 = rb * 16;

#pragma unroll
  for (int it = 0; it < 3; ++it) {
    const int idx = t + it * 256;
    if (idx < 640) {
      const int row = idx / 40, oct = idx - row * 40;
      const float4 v0 = *(const float4*)&h[(row0 + row) * 320 + oct * 8];
      const float4 v1 = *(const float4*)&h[(row0 + row) * 320 + oct * 8 + 4];
      ushort4* dst = (ushort4*)&s_h[(oct * 16 + row) * 8];
      dst[0] = make_ushort4(f2bf(v0.x), f2bf(v0.y), f2bf(v0.z), f2bf(v0.w));
      dst[1] = make_ushort4(f2bf(v1.x), f2bf(v1.y), f2bf(v1.z), f2bf(v1.w));
    }
  }
  __syncthreads();

  f32x4 acc1[5];
#pragma unroll
  for (int u = 0; u < 5; ++u) acc1[u] = (f32x4){0.f, 0.f, 0.f, 0.f};
  const unsigned short* __restrict__ B1m = TB1 + m * 102400;
#pragma unroll
  for (int ks = 0; ks < 10; ++ks) {
    const bf16x8 afr = *(const bf16x8*)&s_h[((ks * 4 + lg) * 16 + lr) * 8];
    bf16x8 bfr[5];
#pragma unroll
    for (int u = 0; u < 5; ++u)
      bfr[u] = *(const bf16x8*)&B1m[((ks * 4 + lg) * 320 + w * 80 + u * 16 + lr) * 8];
#pragma unroll
    for (int u = 0; u < 5; ++u)
      acc1[u] = __builtin_amdgcn_mfma_f32_16x16x32_bf16(afr, bfr[u], acc1[u], 0, 0, 0);
  }
#pragma unroll
  for (int u = 0; u < 5; ++u) {
    const int n = w * 80 + u * 16 + lr;
    const float bias = tb1[m * 320 + n];
#pragma unroll
    for (int r = 0; r < 4; ++r) {
      const int row = lg * 4 + r;
      s_t[((n >> 3) * 16 + row) * 8 + (n & 7)] =
          f2bf(fmaxf(acc1[u][r] + bias, 0.0f));
    }
  }
  __syncthreads();

  const int nb = (w == 0) ? 0 : (w == 1) ? 3 : (w == 2) ? 6 : 7;
  f32x4 acc2[3];
#pragma unroll
  for (int u = 0; u < 3; ++u) acc2[u] = (f32x4){0.f, 0.f, 0.f, 0.f};
  const unsigned short* __restrict__ B2m = TB2 + m * 51200;
#pragma unroll
  for (int ks = 0; ks < 10; ++ks) {
    const bf16x8 afr = *(const bf16x8*)&s_t[((ks * 4 + lg) * 16 + lr) * 8];
    bf16x8 bfr[3];
#pragma unroll
    for (int u = 0; u < 3; ++u)
      bfr[u] = *(const bf16x8*)&B2m[((ks * 4 + lg) * 160 + (nb + u) * 16 + lr) * 8];
#pragma unroll
    for (int u = 0; u < 3; ++u)
      acc2[u] = __builtin_amdgcn_mfma_f32_16x16x32_bf16(afr, bfr[u], acc2[u], 0, 0, 0);
  }
#pragma unroll
  for (int u = 0; u < 3; ++u) {
    const int n = (nb + u) * 16 + lr;
    const float bias = tb2[m * 160 + n];
#pragma unroll
    for (int r = 0; r < 4; ++r) {
      const int row = row0 + lg * 4 + r;
      out[(row * 6 + m) * 160 + n] = acc2[u][r] + bias;
    }
  }
}

// ---------------------------------------------------------------------------
extern "C" void kernel_launch(void* const* d_in, const int* in_sizes, int n_in,
                              void* d_out, int out_size, void* d_ws, size_t ws_size,
                              hipStream_t stream) {
  (void)in_sizes; (void)n_in; (void)out_size; (void)ws_size;
  const float* feat  = (const float*)d_in[0];
  const float* attr  = (const float*)d_in[1];
  const float* pos   = (const float*)d_in[3];
  const float* encW1 = (const float*)d_in[4];
  const float* encb1 = (const float*)d_in[5];
  const float* encW2 = (const float*)d_in[6];
  const float* encb2 = (const float*)d_in[7];
  const float* edgW1 = (const float*)d_in[12];
  const float* edgb1 = (const float*)d_in[13];
  const float* edgW2 = (const float*)d_in[14];
  const float* edgb2 = (const float*)d_in[15];
  const float* Wih   = (const float*)d_in[16];
  const float* Whh   = (const float*)d_in[17];
  const float* bih   = (const float*)d_in[18];
  const float* bhh   = (const float*)d_in[19];
  const float* mW1   = (const float*)d_in[20];
  const float* mb1   = (const float*)d_in[21];
  const float* mW2   = (const float*)d_in[22];
  const float* mb2   = (const float*)d_in[23];
  const float* tW1   = (const float*)d_in[24];
  const float* tb1   = (const float*)d_in[25];
  const float* tW2   = (const float*)d_in[26];
  const float* tb2   = (const float*)d_in[27];

  float* out = (float*)d_out;
  float* ws  = (float*)d_ws;
  float* ctx  = ws;                       // 512*320
  float* P    = ws + 163840;
  float* Q    = ws + 327680;
  float* agg  = ws + 491520;
  float* hbuf = ws + 655360;
  unsigned short* ub = (unsigned short*)(ws + 819200);
  unsigned short* W2bf  = ub;             // 102400 u
  unsigned short* WihBf = ub + 102400;    // 614400 u
  unsigned short* WhhBf = ub + 716800;    // 307200 u
  unsigned short* T1bf  = ub + 1024000;   // 614400 u
  unsigned short* T2bf  = ub + 1638400;   // 307200 u
  unsigned short* EW1bf = ub + 1945600;   // 204800 u
  unsigned short* MW1bf = ub + 2150400;   // 102400 u
  unsigned short* MW2bf = ub + 2252800;   // 5120 u (padded N=16)

  k_head<<<1231, 256, 0, stream>>>(edgW2, Wih, Whh, tW1, tW2, edgW1, mW1, mW2, ub,
                                   feat, attr, encW1, encb1, encW2, encb2, ctx);
  k_pqM<<<dim3(32, 2), 256, 0, stream>>>(ctx, EW1bf, edgb1, P, Q);
  k_edge<<<512, 256, 0, stream>>>(P, Q, pos, edgW1, W2bf, edgb2, agg);
  k_gruM<<<160, 256, 0, stream>>>(ctx, agg, WihBf, WhhBf, bih, bhh, hbuf);
  k_tail<<<208, 256, 0, stream>>>(hbuf, MW1bf, mb1, MW2bf, mb2,
                                  T1bf, tb1, T2bf, tb2, out);
}